// Round 11
// baseline (1575.115 us; speedup 1.0000x reference)
//
#include <hip/hip_runtime.h>

typedef unsigned short u16;
typedef unsigned int   u32;
typedef __attribute__((ext_vector_type(8))) short short8;   // 8 x bf16 (4 VGPRs)
typedef __attribute__((ext_vector_type(4))) float f32x4;    // MFMA accumulator

__device__ __forceinline__ float bf2f(u16 u){ return __uint_as_float(((u32)u)<<16); }
__device__ __forceinline__ u16 f2bf(float f){ u32 x = __float_as_uint(f); x += 0x7fffu + ((x>>16)&1u); return (u16)(x>>16); }
__device__ __forceinline__ float lrelu_f(float v){ return v >= 0.0f ? v : 0.01f*v; }

#if defined(__has_builtin)
#if __has_builtin(__builtin_amdgcn_global_load_lds)
#define HAS_GLL 1
#endif
#endif
#ifndef HAS_GLL
#define HAS_GLL 0
#endif

#if HAS_GLL
// async global->LDS DMA, 16B per lane; LDS dst = l + lane*16 (wave-uniform l)
__device__ __forceinline__ void gll16(const u16* g, u16* l){
  __builtin_amdgcn_global_load_lds(
      (__attribute__((address_space(1))) void*)(void*)g,
      (__attribute__((address_space(3))) void*)l, 16, 0, 0);
}
#endif

// ---------------------------------------------------------------------------
// Implicit-GEMM conv: Out[pm][co] = epi( sum_k A1[pm][k]*B1[co][k] (+phase2) )
// A1 row for pm=(z,lo) is the CONTIGUOUS window at A1 + z*Abatch1 + lo*Arow1
// (caller pre-offsets by -P*Cin), k = tap*Cin + ci.
// Block tile 128(M) x 256(N), BK=64. 4 waves = 2(M)x2(N), each 64x128 via
// 4x8 of 16x16x32 bf16 MFMA (acc[4][8] = 128 AGPRs; single live B-frag).
// Rationale (r10 counters): residency is pinned at ~2 blocks/CU by the
// unified VGPR+AGPR file, so full-N tiles halve A fetch and double MFMA
// per staging barrier at no occupancy cost. N must be a multiple of 256
// at tile granularity (all call sites: 256 or 768).
// 1D grid, XCD-aware decode (Mblks%8==0): consecutive bids walk mblk within
// a group of 8 -> bid%8 XCD round-robin keeps m-locality per XCD.
// LDS: XOR-swizzled (chunk c of row r at slot c^(r&7)), A 16KB + B 32KB.
// DUAL: identity phase-2; epilogue transform applied in-place at boundary.
// ---------------------------------------------------------------------------
template<bool PRED1, bool DUAL, bool F32OUT>
__global__ __launch_bounds__(256, 2) void gemm_conv(
    const u16* __restrict__ A1, const u16* __restrict__ B1,
    const u16* __restrict__ A2, const u16* __restrict__ B2,
    void* __restrict__ Out, const float* __restrict__ scale,
    const float* __restrict__ bias,
    int K1, int K2, int lgLo, int S1, int lgCin1, int P1, int Lin1,
    int Abatch1, int Arow1, int Abatch2, int Arow2,
    int Ncols, int Cout, int lrelu, int Mblks, int Nblks)
{
  __shared__ u16 ldsA[128*64];
  __shared__ u16 ldsB[256*64];
  const int tid = threadIdx.x;
  int nblk, mblk;
  {
    const int bid = blockIdx.x;
    if (Mblks & 7){ nblk = bid % Nblks; mblk = bid / Nblks; }
    else { const int grp = Nblks*8; const int g = bid/grp; const int r = bid - g*grp;
           nblk = r >> 3; mblk = g*8 + (r & 7); }
  }
  const int wv = tid >> 6, lane = tid & 63;
  const int mbase = (wv & 1)*64, nbase = (wv >> 1)*128;
  const int lq = lane >> 4, lm = lane & 15;
  const int sw = lm & 7;                            // fragment-read swizzle key

  f32x4 acc[4][8];
#pragma unroll
  for (int a_=0;a_<4;a_++)
#pragma unroll
    for (int b_=0;b_<8;b_++) acc[a_][b_] = (f32x4){0.f,0.f,0.f,0.f};

  float scv[8], biv[8];
  if constexpr (DUAL){
#pragma unroll
    for (int nt=0;nt<8;nt++){
      const int colg = nblk*256 + nbase + nt*16 + lm;   // DUAL: Ncols==256, in-range
      scv[nt] = scale[colg]; biv[nt] = bias[colg];
    }
  }

  auto mfma_step = [&](){
#pragma unroll
    for (int kk=0; kk<2; kk++){
      const int s8 = (((kk*4+lq) ^ sw) << 3);
      short8 af[4];
#pragma unroll
      for (int mt=0;mt<4;mt++) af[mt] = *(const short8*)&ldsA[(mbase+mt*16+lm)*64 + s8];
#pragma unroll
      for (int nt=0;nt<8;nt++){
        const short8 bfr = *(const short8*)&ldsB[(nbase+nt*16+lm)*64 + s8];
#pragma unroll
        for (int mt=0;mt<4;mt++)
          acc[mt][nt] = __builtin_amdgcn_mfma_f32_16x16x32_bf16(af[mt], bfr, acc[mt][nt], 0,0,0);
      }
    }
  };
  auto xform = [&](){                     // in-place epilogue at phase boundary
#pragma unroll
    for (int mt=0;mt<4;mt++)
#pragma unroll
      for (int nt=0;nt<8;nt++)
#pragma unroll
        for (int r=0;r<4;r++){
          float v = acc[mt][nt][r]*scv[nt] + biv[nt];
          acc[mt][nt][r] = lrelu ? lrelu_f(v) : v;
        }
  };

  const int Ktot = DUAL ? (K1 + K2) : K1;

  // wave-uniform interior test: unpredicated A reads for the whole m-tile?
  bool fast = (HAS_GLL != 0);
  if (PRED1 && fast){
    const int Lo = 1 << lgLo;
    if (Lo < 128) fast = false;
    else {
      const int lo0 = (mblk*128) & (Lo-1);
      const int taps = K1 >> lgCin1;
      fast = (lo0*S1 - P1 >= 0) && ((lo0+127)*S1 + taps - 1 - P1 < Lin1);
    }
  }

#if HAS_GLL
  if (fast){
    // Fast path: Lo>=128, tiles 128-aligned -> z constant per tile.
    const int pm0 = mblk*128;
    const int z0  = pm0 >> lgLo;
    const int lo0 = pm0 & ((1<<lgLo)-1);
    const int lr  = lane >> 3;
    const int lc8 = (lane & 7) ^ lr;              // swizzled chunk for this lane
    // A: 4 waves x 32 rows; B: 4 waves x 64 rows (256 total)
    const u16* pA = A1 + (long)z0*Abatch1 + (long)(lo0 + wv*32 + lr)*Arow1 + lc8*8;
    const u16* pB = B1 + (long)(nblk*256 + wv*64 + lr)*K1 + lc8*8;
    long strA = Arow1, strB = K1;
    u16* da = &ldsA[(wv*32)*64];
    u16* db = &ldsB[(wv*64)*64];
    for (int k0 = 0; k0 < Ktot; k0 += 64){
      int kk = k0;
      if constexpr (DUAL){
        if (k0 >= K1){
          if (k0 == K1){
            pA = A2 + (long)z0*Abatch2 + (long)(lo0 + wv*32 + lr)*Arow2 + lc8*8;
            pB = B2 + (long)(nblk*256 + wv*64 + lr)*K2 + lc8*8;
            strA = Arow2; strB = K2;
          }
          kk = k0 - K1;
        }
      }
      __syncthreads();
#pragma unroll
      for (int u=0; u<4; u++) gll16(pA + (long)u*8*strA + kk, da + u*8*64);
#pragma unroll
      for (int u=0; u<8; u++) gll16(pB + (long)u*8*strB + kk, db + u*8*64);
      __syncthreads();      // drains DMA -> writes visible
      if constexpr (DUAL){ if (k0 == K1) xform(); }
      mfma_step();
    }
  } else
#endif
  {
    // predicated VGPR staging (zero-fills OOB taps), swizzled layout
    const int sr  = tid >> 1;              // A: 2 threads/row, 128 rows
    const int cg  = (tid & 1)*4;
    const int pmS = mblk*128 + sr;
    const int zS  = pmS >> lgLo;
    const int loS = pmS & ((1<<lgLo)-1);
    const long aoff1 = (long)zS*Abatch1 + (long)loS*Arow1;
    long aoff2 = 0;
    if constexpr (DUAL) aoff2 = (long)zS*Abatch2 + (long)loS*Arow2;
    const long boff1 = (long)(nblk*256 + tid)*K1;   // B: 1 thread/row, 256 rows
    long boff2 = 0;
    if constexpr (DUAL) boff2 = (long)(nblk*256 + tid)*K2;
    const int ssw = sr & 7;
    const int bsw = tid & 7;

    for (int k0 = 0; k0 < Ktot; k0 += 64){
      const bool ph1 = !DUAL || (k0 < K1);
      __syncthreads();
      {
        const u16* asrc = ph1 ? (A1 + aoff1 + k0) : (A2 + aoff2 + (k0 - K1));
#pragma unroll
        for (int u=0; u<4; u++){
          const int c = cg + u;
          uint4 v; v.x=0u; v.y=0u; v.z=0u; v.w=0u;
          bool ok = true;
          if (PRED1 && ph1){
            int tap = (k0 + c*8) >> lgCin1;
            int pos = loS*S1 + tap - P1;
            ok = ((u32)pos < (u32)Lin1);
          }
          if (ok) v = *(const uint4*)(asrc + c*8);
          *(uint4*)&ldsA[sr*64 + ((c ^ ssw)*8)] = v;
        }
      }
      {
        const u16* bsrc = ph1 ? (B1 + boff1 + k0) : (B2 + boff2 + (k0 - K1));
#pragma unroll
        for (int c=0; c<8; c++){
          uint4 v = *(const uint4*)(bsrc + c*8);
          *(uint4*)&ldsB[tid*64 + ((c ^ bsw)*8)] = v;
        }
      }
      __syncthreads();
      if constexpr (DUAL){ if (k0 == K1) xform(); }
      mfma_step();
    }
  }

  // epilogue: DUAL acc is already final (transform applied at boundary + id)
#pragma unroll
  for (int nt=0;nt<8;nt++){
    const int colg = nblk*256 + nbase + nt*16 + lm;
    if (colg >= Ncols) continue;
    float sc = 1.0f, bi = 0.0f;
    if constexpr (!DUAL){
      if (scale) sc = scale[colg];
      if (bias)  bi = bias[colg];
    }
#pragma unroll
    for (int mt=0;mt<4;mt++){
#pragma unroll
      for (int r=0;r<4;r++){
        const long pm = (long)mblk*128 + mbase + mt*16 + lq*4 + r;
        float v = acc[mt][nt][r];
        if constexpr (!DUAL){
          v = v*sc + bi;
          if (lrelu) v = lrelu_f(v);
        }
        if constexpr (F32OUT) ((float*)Out)[pm*Cout + colg] = v;
        else                  ((u16*)Out)[pm*Cout + colg] = f2bf(v);
      }
    }
  }
}

// --------------------------- prep kernels (fp32 -> bf16) --------------------
__global__ void bnfold_kernel(
    const float* __restrict__ bn0, const float* __restrict__ rbn1, const float* __restrict__ rbn2,
    float* s0, float* b0, float* s1, float* b1, float* s2, float* b2)
{
  const int blk = blockIdx.x, t = threadIdx.x;   // t < 256
  const float* p; float *so, *bo;
  if (blk == 0){ p = bn0; so = s0; bo = b0; }
  else if (blk <= 5){ int i = blk-1; p = rbn1 + i*1024; so = s1+i*256; bo = b1+i*256; }
  else { int i = blk-6; p = rbn2 + i*1024; so = s2+i*256; bo = b2+i*256; }
  const float g = p[t], be = p[256+t], m = p[512+t], v = p[768+t];
  const float sc = g / sqrtf(v + 1e-5f);
  so[t] = sc; bo[t] = be - m*sc;
}

__global__ void w0prep_kernel(const float* __restrict__ cw, u16* __restrict__ w0p){
  const int co = blockIdx.x, k = threadIdx.x;
  const int tp = k >> 4, ci = k & 15;
  u16 v = 0;
  if (tp < 15 && ci < 12) v = f2bf(cw[(co*12 + ci)*15 + tp]);
  w0p[co*256 + k] = v;
}

__global__ void wrprep_kernel(const float* __restrict__ c1, const float* __restrict__ c2, u16* __restrict__ wr){
  const int co = blockIdx.x, slot = blockIdx.y, ci = threadIdx.x;
  const float* src = (slot < 5) ? (c1 + (size_t)slot*589824) : (c2 + (size_t)(slot-5)*589824);
  u16* dst = wr + (size_t)slot*589824 + (size_t)co*2304;
  for (int tp=0; tp<9; tp++) dst[tp*256 + ci] = f2bf(src[(co*256 + ci)*9 + tp]);
}

__global__ void widprep_kernel(const float* __restrict__ idw, u16* __restrict__ wid){
  const int co = blockIdx.x, sl = blockIdx.y, ci = threadIdx.x;
  u16 h = f2bf(0.5f * idw[((size_t)sl*256 + co)*256 + ci]);
  u16* dst = wid + (size_t)sl*131072 + co*512;
  dst[ci] = h; dst[256 + ci] = h;
}

__global__ void x16prep_kernel(const float* __restrict__ x, u16* __restrict__ x16){
  const int p = blockIdx.x*256 + threadIdx.x;
  const int b = blockIdx.y;
  u16 v[16];
#pragma unroll
  for (int ci=0; ci<16; ci++) v[ci] = (ci < 12) ? f2bf(x[((size_t)(b*12+ci))*4096 + p]) : (u16)0;
  uint4 A4, B4;
  A4.x = v[0] | ((u32)v[1]<<16); A4.y = v[2] | ((u32)v[3]<<16);
  A4.z = v[4] | ((u32)v[5]<<16); A4.w = v[6] | ((u32)v[7]<<16);
  B4.x = v[8] | ((u32)v[9]<<16); B4.y = v[10]| ((u32)v[11]<<16);
  B4.z = v[12]| ((u32)v[13]<<16); B4.w = v[14]| ((u32)v[15]<<16);
  uint4* dst = (uint4*)&x16[((size_t)b*4096 + p)*16];
  dst[0] = A4; dst[1] = B4;
}

// generic fp32 -> bf16 cast
__global__ void castb_kernel(const float* __restrict__ src, u16* __restrict__ dst, int n){
  const int i = blockIdx.x*256 + threadIdx.x;
  if (i < n) dst[i] = f2bf(src[i]);
}

__global__ void canary_kernel(float* __restrict__ outp){
  const int idx = blockIdx.x*256 + threadIdx.x;
  if (idx < 3456) outp[idx] = 131072.0f;
}

// --------------------------- fp32 kernels (verified round 4-10) -------------
__global__ __launch_bounds__(256) void dconv1(
    const float* __restrict__ in, long inSS,
    const float* __restrict__ w, const float* __restrict__ bn, int Cst,
    const float* __restrict__ cb,
    float* __restrict__ out, long outSS,
    int KT, int S, int P, int Lin, int Lo)
{
  __shared__ float ldw[64];
  const int co = blockIdx.y, z = blockIdx.z;
  if (threadIdx.x < KT) ldw[threadIdx.x] = w[(size_t)co*KT + threadIdx.x];
  __syncthreads();
  const int o = blockIdx.x*256 + threadIdx.x;
  if (o >= Lo) return;
  const float* ip = in + (long)z*inSS;
  float acc = cb[co];
  const int base = o*S - P;
  for (int t = 0; t < KT; t++){
    const int pos = base + t;
    if ((u32)pos < (u32)Lin) acc += ldw[t]*ip[pos];
  }
  const float g = bn[co], be = bn[Cst+co], m = bn[2*Cst+co], v = bn[3*Cst+co];
  const float sc = g/sqrtf(v + 1e-5f);
  out[(long)z*outSS + (size_t)co*Lo + o] = lrelu_f((acc - m)*sc + be);
}

// attention; qkv (rows,768) fp32 -> o (rows,256) bf16; rows = 64*samples
__global__ __launch_bounds__(256) void attn2b(const float* __restrict__ qkv, u16* __restrict__ o){
  const int gt = blockIdx.x*256 + threadIdx.x;
  const int q = gt & 63, h = (gt>>6) & 7, bl = gt >> 9;
  const float* qp = qkv + ((size_t)(bl*64 + q))*768 + h*32;
  float qv[32];
#pragma unroll
  for (int d = 0; d < 32; d++) qv[d] = qp[d];
  float s[64]; float mx = -1e30f;
  const float isq = 0.17677669529663687f;        // 1/sqrt(32)
  for (int kc = 0; kc < 64; kc++){
    const float* kp = qkv + ((size_t)(bl*64 + kc))*768 + 256 + h*32;
    float dot = 0.f;
#pragma unroll
    for (int d = 0; d < 32; d++) dot += qv[d]*kp[d];
    dot *= isq; s[kc] = dot; mx = fmaxf(mx, dot);
  }
  float sum = 0.f;
  for (int kc = 0; kc < 64; kc++){ float e = __expf(s[kc]-mx); s[kc] = e; sum += e; }
  const float inv = 1.0f/sum;
  float ov[32];
#pragma unroll
  for (int d = 0; d < 32; d++) ov[d] = 0.f;
  for (int kc = 0; kc < 64; kc++){
    const float* vp = qkv + ((size_t)(bl*64 + kc))*768 + 512 + h*32;
    const float wgt = s[kc];
#pragma unroll
    for (int d = 0; d < 32; d++) ov[d] += wgt*vp[d];
  }
  u16* op = o + ((size_t)(bl*64 + q))*256 + h*32;
#pragma unroll
  for (int d = 0; d < 32; d++) op[d] = f2bf(ov[d]*inv);
}

__global__ void xmain_s(const float* __restrict__ om, float* __restrict__ xm, int b0){
  const int e = threadIdx.x, bl = blockIdx.x;
  float m = -1e30f;
  for (int s = 0; s < 64; s++) m = fmaxf(m, om[((size_t)(bl*64+s))*256 + e]);
  xm[(size_t)(b0+bl)*256 + e] = m;
}

__global__ void flutpool_s(const float* __restrict__ act, float* __restrict__ fp, int b0){
  const int c = threadIdx.x, g = blockIdx.x, bl = blockIdx.y;
  const float* a = act + ((size_t)bl*64 + c)*2048;
  float m = -1e30f;
  for (int i = 0; i < 32; i++) m = fmaxf(m, a[g*32+i]);
  fp[(size_t)(b0+bl)*4096 + c*64 + g] = m;
}
__global__ void pvcpool_s(const float* __restrict__ act, float* __restrict__ pp, int b0){
  const int c = threadIdx.x, g = blockIdx.x, bl = blockIdx.y;
  const float* a = act + ((size_t)bl*64 + c)*2048;
  float m = -1e30f;
  for (int i = 0; i < 64; i++) m = fmaxf(m, a[g*64+i]);
  pp[(size_t)(b0+bl)*2048 + c*32 + g] = m;
}

// FC dot-product: one block per output scalar (b,j); float4 K-reduction.
template<int N, int K>
__global__ __launch_bounds__(256) void fcdot_kernel(const float* __restrict__ inp,
    const float* __restrict__ w, float* __restrict__ outp)
{
  const int b = blockIdx.x, j = blockIdx.y;
  const int t = threadIdx.x;
  const float4* x4 = (const float4*)(inp + (size_t)b*K);
  const float4* w4 = (const float4*)(w   + (size_t)j*K);
  float s = 0.f;
#pragma unroll
  for (int k = t; k < K/4; k += 256){
    const float4 a = x4[k], c = w4[k];
    s += a.x*c.x + a.y*c.y + a.z*c.z + a.w*c.w;
  }
  for (int o2 = 32; o2 > 0; o2 >>= 1) s += __shfl_down(s, o2, 64);
  __shared__ float red[4];
  const int wv = t >> 6, lane = t & 63;
  if (lane == 0) red[wv] = s;
  __syncthreads();
  if (t == 0) outp[(size_t)b*N + j] = lrelu_f(red[0]+red[1]+red[2]+red[3]);
}

// DFT magnitudes via twiddle recurrence (2 sincos + 15 rotations per thread)
__global__ __launch_bounds__(256) void fft_kernel(const float* __restrict__ x, float* __restrict__ mag){
  const int blk = blockIdx.x;              // 64*256
  const int b = blk >> 8, kk = blk & 255, bin = kk + 50;
  const int t = threadIdx.x;
  const float* xp = x + ((size_t)(b*12 + 1))*4096;
  const float C = 6.283185307179586f/4096.0f;
  float cr, si;  __sincosf((float)((bin*t)   & 4095)*C, &si, &cr);
  float cS, sS;  __sincosf((float)((bin*256) & 4095)*C, &sS, &cS);
  float re = 0.f, im = 0.f;
  for (int n = t; n < 4096; n += 256){
    const float xv = xp[n];
    re += xv*cr; im += xv*si;
    const float c2 = cr*cS - si*sS;
    si = cr*sS + si*cS;
    cr = c2;
  }
  __shared__ float rr[256], ri[256];
  rr[t] = re; ri[t] = im; __syncthreads();
  for (int o2 = 128; o2 > 0; o2 >>= 1){ if (t < o2){ rr[t]+=rr[t+o2]; ri[t]+=ri[t+o2]; } __syncthreads(); }
  if (t == 0) mag[b*256 + kk] = sqrtf(rr[0]*rr[0] + ri[0]*ri[0]);
}

__global__ void rowmax_kernel(const float* __restrict__ mag, float* __restrict__ rmax){
  const int b = blockIdx.x, t = threadIdx.x;
  __shared__ float r[256];
  r[t] = mag[b*256 + t]; __syncthreads();
  for (int o2 = 128; o2 > 0; o2 >>= 1){ if (t < o2) r[t] = fmaxf(r[t], r[t+o2]); __syncthreads(); }
  if (t == 0) rmax[b] = r[0];
}

__global__ void freq_kernel(const float* __restrict__ mag, const float* __restrict__ rmax,
                            const float* __restrict__ fw, const float* __restrict__ fb,
                            float* __restrict__ outp){
  const int b = blockIdx.x, j = threadIdx.x;  // 32
  const float mx = rmax[b];
  const float sc = mx > 0.f ? 1.0f/mx : 1.0f;
  float acc = fb[j];
  for (int i = 0; i < 256; i++) acc += (mag[b*256+i]*sc) * fw[(size_t)j*256 + i];
  outp[b*32 + j] = lrelu_f(acc);
}

__global__ void final_kernel(const float* __restrict__ xm, const float* __restrict__ l,
                             const float* __restrict__ fr, const float* __restrict__ fv,
                             const float* __restrict__ pv, const float* __restrict__ fcw,
                             const float* __restrict__ fcb, float* __restrict__ outp){
  const int b = blockIdx.x, j = threadIdx.x;  // 32 threads, 27 active
  if (j >= 27) return;
  float acc = fcb[j];
  const float* wr_ = fcw + (size_t)j*396;
  for (int i = 0; i < 256; i++) acc += xm[b*256+i] * wr_[i];
  for (int i = 0; i < 12;  i++) acc += l[b*12+i]   * wr_[256+i];
  for (int i = 0; i < 32;  i++) acc += fr[b*32+i]  * wr_[268+i];
  for (int i = 0; i < 64;  i++) acc += fv[b*64+i]  * wr_[300+i];
  for (int i = 0; i < 32;  i++) acc += pv[b*32+i]  * wr_[364+i];
  outp[b*27 + j] = acc;
  outp[64*27 + b*27 + j] = 1.0f/(1.0f + __expf(-acc));
}

// --------------------------- host side --------------------------------------
extern "C" void kernel_launch(void* const* d_in, const int* in_sizes, int n_in,
                              void* d_out, int out_size, void* d_ws, size_t ws_size,
                              hipStream_t stream)
{
  const float* x       = (const float*)d_in[0];
  const float* l       = (const float*)d_in[1];
  const float* conv_w  = (const float*)d_in[2];
  const float* bn0     = (const float*)d_in[3];
  const float* rb_c1   = (const float*)d_in[4];
  const float* rb_bn1  = (const float*)d_in[5];
  const float* rb_c2   = (const float*)d_in[6];
  const float* rb_bn2  = (const float*)d_in[7];
  const float* rb_id   = (const float*)d_in[8];
  const float* in_w    = (const float*)d_in[9];
  const float* in_b    = (const float*)d_in[10];
  const float* out_w   = (const float*)d_in[11];
  const float* out_b   = (const float*)d_in[12];
  const float* flut_w  = (const float*)d_in[13];
  const float* flut_b  = (const float*)d_in[14];
  const float* flut_bn = (const float*)d_in[15];
  const float* pvc_w   = (const float*)d_in[16];
  const float* pvc_b   = (const float*)d_in[17];
  const float* pvc_bn  = (const float*)d_in[18];
  const float* w_flut2 = (const float*)d_in[19];
  const float* w_pvc2  = (const float*)d_in[20];
  const float* freq_w  = (const float*)d_in[21];
  const float* freq_b  = (const float*)d_in[22];
  const float* fc_w    = (const float*)d_in[23];
  const float* fc_b    = (const float*)d_in[24];
  float* outp = (float*)d_out;

  char* ws = (char*)d_ws;
  size_t off = 0;
  auto alloc = [&](size_t bytes)->char*{ char* p = ws + off; off = (off + bytes + 255) & ~(size_t)255; return p; };

  // ---- persistent (~16.7 MiB) ----
  u16* wr    = (u16*)alloc((size_t)10*589824*2);   // 11.25 MiB res weights [slot][co][tap*256+ci]
  u16* wid   = (u16*)alloc((size_t)5*131072*2);    //  1.25 MiB identity 2-tap weights
  u16* w0p   = (u16*)alloc(131072);                //  conv0 weights, K-padded
  u16* wqkvb = (u16*)alloc(196608*2);              //  qkv proj weights bf16 (768,256)
  u16* woutb = (u16*)alloc(65536*2);               //  out proj weights bf16 (256,256)
  u16* h5b   = (u16*)alloc((size_t)64*64*256*2);   //  2 MiB (B*64,256) bf16
  float* s0 = (float*)alloc(1024);  float* b0 = (float*)alloc(1024);
  float* s1 = (float*)alloc(5120);  float* b1 = (float*)alloc(5120);
  float* s2 = (float*)alloc(5120);  float* b2 = (float*)alloc(5120);
  float* xm    = (float*)alloc(65536);
  float* fpool = (float*)alloc((size_t)64*4096*4); // 1 MiB
  float* ppool = (float*)alloc((size_t)64*2048*4); // 0.5 MiB
  float* mag   = (float*)alloc(65536);
  float* rmax  = (float*)alloc(1024);
  float* fvecv = (float*)alloc(16384);
  float* pvecv = (float*)alloc(8192);
  float* freqv = (float*)alloc(8192);

  // ---- adaptive batch slice: chain arena = 2.625*sp MiB (bf16 activations) ----
  const size_t rem = (ws_size > off) ? (ws_size - off) : 0;
  int sp = 0;
  for (int c = 64; c >= 2; c >>= 1)
    if ((size_t)c*2752512 + (1<<20) <= rem){ sp = c; break; }
  if (sp == 0){ canary_kernel<<<14,256,0,stream>>>(outp); return; }

  u16* x16q = (u16*)alloc((size_t)sp*131072);      // (sp,4096,16) bf16
  u16* h0q  = (u16*)alloc((size_t)sp*1048576);     // (sp,2048,256) bf16
  u16* hCq  = (u16*)alloc((size_t)sp*524288);      // (sp,<=1024,256) bf16
  u16* ping = (u16*)alloc((size_t)sp*524288);
  u16* pong = (u16*)alloc((size_t)sp*524288);

  // ---- param prep (once) ----
  bnfold_kernel<<<11,256,0,stream>>>(bn0, rb_bn1, rb_bn2, s0,b0,s1,b1,s2,b2);
  w0prep_kernel<<<256,256,0,stream>>>(conv_w, w0p);
  wrprep_kernel<<<dim3(256,10),256,0,stream>>>(rb_c1, rb_c2, wr);
  widprep_kernel<<<dim3(256,5),256,0,stream>>>(rb_id, wid);
  castb_kernel<<<768,256,0,stream>>>(in_w, wqkvb, 196608);
  castb_kernel<<<256,256,0,stream>>>(out_w, woutb, 65536);

  // ---- res chain: (64/sp) slices on the MFMA engine (1D grid, 256-wide N) ----
  for (int s = 0; s < 64/sp; s++){
    const float* xs = x + (size_t)s*sp*49152;
    x16prep_kernel<<<dim3(16,sp),256,0,stream>>>(xs, x16q);
    // conv0: (sp,4096,16) -> (sp,2048,256), k=15 s=2 p=7, K padded to 256
    {
      const int mm = sp*16, nn = 1;
      gemm_conv<true,false,false><<<mm*nn,256,0,stream>>>(
          x16q - 112, w0p, nullptr, nullptr, h0q, s0, b0,
          256, 0, 11, 2, 4, 7, 4096, 65536, 32, 0, 0, 256, 256, 1, mm, nn);
    }
    int Lin = 2048;
    const u16* bin = h0q;
    for (int i = 0; i < 5; i++){
      const int Lo = Lin >> 1;
      const int mm = sp*Lo/128, nn = 1;
      const int lgLo = 10 - i;
      // conv1 (k=9,s=2,p=4) + bn1 + lrelu
      gemm_conv<true,false,false><<<mm*nn,256,0,stream>>>(
          bin - 1024, wr + (size_t)i*589824, nullptr, nullptr, hCq, s1+i*256, b1+i*256,
          2304, 0, lgLo, 2, 8, 4, Lin, Lin*256, 512, 0, 0, 256, 256, 1, mm, nn);
      // conv2 (k=9,s=1,p=4) + bn2 + lrelu + fused identity (avgpool2+1x1 as 2-tap)
      if (i < 4){
        u16* bout = (i&1) ? pong : ping;
        gemm_conv<true,true,false><<<mm*nn,256,0,stream>>>(
            hCq - 1024, wr + (size_t)(5+i)*589824, bin, wid + (size_t)i*131072,
            bout, s2+i*256, b2+i*256,
            2304, 512, lgLo, 1, 8, 4, Lo, Lo*256, 256, Lin*256, 512, 256, 256, 1, mm, nn);
        bin = bout;
      } else {
        gemm_conv<true,true,false><<<mm*nn,256,0,stream>>>(
            hCq - 1024, wr + (size_t)(5+i)*589824, bin, wid + (size_t)i*131072,
            h5b + (size_t)s*sp*16384, s2+i*256, b2+i*256,
            2304, 512, lgLo, 1, 8, 4, Lo, Lo*256, 256, Lin*256, 512, 256, 256, 1, mm, nn);
      }
      Lin = Lo;
    }
  }

  // ---- MHA on MFMA GEMMs; slice if arena is small ----
  {
    const int nsl = (sp >= 8) ? 1 : 4;
    const int rows = 4096/nsl;                       // 64*samples per slice
    float* qkvF = (float*)x16q;                      // arena aliases (chain is dead)
    u16*   o_b  = (u16*)(qkvF + (size_t)rows*768);
    float* omF  = (float*)(o_b + (size_t)rows*256);
    for (int s = 0; s < nsl; s++){
      const int mm = rows/128;
      gemm_conv<false,false,true><<<mm*3,256,0,stream>>>(
          h5b + (size_t)s*rows*256, wqkvb, nullptr, nullptr, qkvF, nullptr, in_b,
          256, 0, 12, 1, 8, 0, 0, 0, 256, 0, 0, 768, 768, 0, mm, 3);
      attn2b<<<rows/32,256,0,stream>>>(qkvF, o_b);
      gemm_conv<false,false,true><<<mm*1,256,0,stream>>>(
          o_b, woutb, nullptr, nullptr, omF, nullptr, out_b,
          256, 0, 12, 1, 8, 0, 0, 0, 256, 0, 0, 256, 256, 0, mm, 1);
      xmain_s<<<rows/64,256,0,stream>>>(omF, xm, s*(rows/64));
    }
  }

  // ---- lead_II branch (fp32 direct, verified) ----
  {
    float* act = (float*)x16q;                       // arena alias
    const int nz = (sp >= 16) ? 64 : 8;              // act = nz*64*2048*4 bytes
    for (int s = 0; s < 64/nz; s++){
      const float* xs = x + ((size_t)(s*nz)*12 + 1)*4096;
      dconv1<<<dim3(8,64,nz),256,0,stream>>>(xs, 49152, flut_w, flut_bn, 64, flut_b,
                                             act, 64*2048, 15, 2, 7, 4096, 2048);
      flutpool_s<<<dim3(64,nz),64,0,stream>>>(act, fpool, s*nz);
      dconv1<<<dim3(8,64,nz),256,0,stream>>>(xs, 49152, pvc_w, pvc_bn, 64, pvc_b,
                                             act, 64*2048, 9, 2, 4, 4096, 2048);
      pvcpool_s<<<dim3(32,nz),64,0,stream>>>(act, ppool, s*nz);
    }
  }
  fcdot_kernel<64,4096><<<dim3(64,64),256,0,stream>>>(fpool, w_flut2, fvecv);
  fcdot_kernel<32,2048><<<dim3(64,32),256,0,stream>>>(ppool, w_pvc2, pvecv);

  // ---- FFT branch ----
  fft_kernel<<<16384,256,0,stream>>>(x, mag);
  rowmax_kernel<<<64,256,0,stream>>>(mag, rmax);
  freq_kernel<<<64,32,0,stream>>>(mag, rmax, freq_w, freq_b, freqv);

  // ---- combine + logits + sigmoid ----
  final_kernel<<<64,32,0,stream>>>(xm, l, freqv, fvecv, pvecv, fc_w, fc_b, outp);
  (void)in_sizes; (void)n_in; (void)out_size;
}

// Round 12
// 1312.752 us; speedup vs baseline: 1.1999x; 1.1999x over previous
//
#include <hip/hip_runtime.h>

typedef unsigned short u16;
typedef unsigned int   u32;
typedef __attribute__((ext_vector_type(8))) short short8;   // 8 x bf16 (4 VGPRs)
typedef __attribute__((ext_vector_type(4))) float f32x4;    // MFMA accumulator

__device__ __forceinline__ float bf2f(u16 u){ return __uint_as_float(((u32)u)<<16); }
__device__ __forceinline__ u16 f2bf(float f){ u32 x = __float_as_uint(f); x += 0x7fffu + ((x>>16)&1u); return (u16)(x>>16); }
__device__ __forceinline__ float lrelu_f(float v){ return v >= 0.0f ? v : 0.01f*v; }

#if defined(__has_builtin)
#if __has_builtin(__builtin_amdgcn_global_load_lds)
#define HAS_GLL 1
#endif
#endif
#ifndef HAS_GLL
#define HAS_GLL 0
#endif

#if HAS_GLL
// async global->LDS DMA, 16B per lane; LDS dst = l + lane*16 (wave-uniform l)
__device__ __forceinline__ void gll16(const u16* g, u16* l){
  __builtin_amdgcn_global_load_lds(
      (__attribute__((address_space(1))) void*)(void*)g,
      (__attribute__((address_space(3))) void*)l, 16, 0, 0);
}
#endif

// ---------------------------------------------------------------------------
// Implicit-GEMM conv: Out[pm][co] = epi( sum_k A1[pm][k]*B1[co][k] (+phase2) )
// A1 row for pm=(z,lo) is the CONTIGUOUS window at A1 + z*Abatch1 + lo*Arow1
// (caller pre-offsets by -P*Cin), k = tap*Cin + ci.
// 1D grid, XCD-aware decode (Mblks%8==0): bids 0..7 -> n0/mblk0..7,
// 8..15 -> n1/same mblks => the n-pair sharing an A tile lands on the SAME
// XCD (blockId%8) -> A fetched once into that XCD L2.
// Tile 128x128, BK=64, 4 waves x (4x4 of 16x16x32 bf16 MFMA).
// SINGLE accumulator: DUAL identity phase applies the epilogue transform
// lrelu(acc*sc+bi) IN-PLACE at the K1->K2 boundary, then phase-2 MFMA
// accumulates raw identity on top. 64 VGPRs + 64 AGPRs -> 4 waves/SIMD
// (__launch_bounds__(256,4)) -> latency hiding (r10: 26% occ, 28% MfmaUtil).
// LDS: XOR-swizzled 128x64 u16 tiles, single-buffered (32 KB).
// NOTE r11: 128x256 full-N tile REGRESSED (occ 15%, FETCH unchanged) — the
// A over-fetch is L2 window-overlap amplification, not n-duplication. Keep
// this 128x128 shape.
// ---------------------------------------------------------------------------
template<bool PRED1, bool DUAL, bool F32OUT>
__global__ __launch_bounds__(256, 4) void gemm_conv(
    const u16* __restrict__ A1, const u16* __restrict__ B1,
    const u16* __restrict__ A2, const u16* __restrict__ B2,
    void* __restrict__ Out, const float* __restrict__ scale,
    const float* __restrict__ bias,
    int K1, int K2, int lgLo, int S1, int lgCin1, int P1, int Lin1,
    int Abatch1, int Arow1, int Abatch2, int Arow2,
    int Ncols, int Cout, int lrelu, int Mblks, int Nblks)
{
  __shared__ u16 ldsA[128*64];
  __shared__ u16 ldsB[128*64];
  const int tid = threadIdx.x;
  int nblk, mblk;
  {
    const int bid = blockIdx.x;
    if (Mblks & 7){ nblk = bid % Nblks; mblk = bid / Nblks; }
    else { const int grp = Nblks*8; const int g = bid/grp; const int r = bid - g*grp;
           nblk = r >> 3; mblk = g*8 + (r & 7); }
  }
  const int wv = tid >> 6, lane = tid & 63;
  const int mbase = (wv & 1)*64, nbase = (wv >> 1)*64;
  const int lq = lane >> 4, lm = lane & 15;
  const int sw = lm & 7;                            // fragment-read swizzle key

  f32x4 acc[4][4];
#pragma unroll
  for (int a_=0;a_<4;a_++)
#pragma unroll
    for (int b_=0;b_<4;b_++) acc[a_][b_] = (f32x4){0.f,0.f,0.f,0.f};

  float scv[4], biv[4];
  if constexpr (DUAL){
#pragma unroll
    for (int nt=0;nt<4;nt++){
      const int colg = nblk*128 + nbase + nt*16 + lm;   // DUAL: Ncols==Cout==256, in-range
      scv[nt] = scale[colg]; biv[nt] = bias[colg];
    }
  }

  auto mfma_step = [&](){
#pragma unroll
    for (int kk=0; kk<2; kk++){
      const int s8 = (((kk*4+lq) ^ sw) << 3);
      short8 af[4], bfr[4];
#pragma unroll
      for (int mt=0;mt<4;mt++) af[mt]  = *(const short8*)&ldsA[(mbase+mt*16+lm)*64 + s8];
#pragma unroll
      for (int nt=0;nt<4;nt++) bfr[nt] = *(const short8*)&ldsB[(nbase+nt*16+lm)*64 + s8];
#pragma unroll
      for (int mt=0;mt<4;mt++)
#pragma unroll
        for (int nt=0;nt<4;nt++)
          acc[mt][nt] = __builtin_amdgcn_mfma_f32_16x16x32_bf16(af[mt], bfr[nt], acc[mt][nt], 0,0,0);
    }
  };
  auto xform = [&](){                     // in-place epilogue at phase boundary
#pragma unroll
    for (int mt=0;mt<4;mt++)
#pragma unroll
      for (int nt=0;nt<4;nt++)
#pragma unroll
        for (int r=0;r<4;r++){
          float v = acc[mt][nt][r]*scv[nt] + biv[nt];
          acc[mt][nt][r] = lrelu ? lrelu_f(v) : v;
        }
  };

  const int Ktot = DUAL ? (K1 + K2) : K1;

  // wave-uniform interior test: unpredicated A reads for the whole m-tile?
  bool fast = (HAS_GLL != 0);
  if (PRED1 && fast){
    const int Lo = 1 << lgLo;
    if (Lo < 128) fast = false;
    else {
      const int lo0 = (mblk*128) & (Lo-1);
      const int taps = K1 >> lgCin1;
      fast = (lo0*S1 - P1 >= 0) && ((lo0+127)*S1 + taps - 1 - P1 < Lin1);
    }
  }

#if HAS_GLL
  if (fast){
    // Fast path: Lo>=128, tiles 128-aligned -> z constant per tile.
    const int pm0 = mblk*128;
    const int z0  = pm0 >> lgLo;
    const int lo0 = pm0 & ((1<<lgLo)-1);
    const int lr  = lane >> 3;
    const int lc8 = (lane & 7) ^ lr;              // swizzled chunk for this lane
    const u16* pA = A1 + (long)z0*Abatch1 + (long)(lo0 + wv*32 + lr)*Arow1 + lc8*8;
    const u16* pB = B1 + (long)(nblk*128 + wv*32 + lr)*K1 + lc8*8;
    long strA = Arow1, strB = K1;
    u16* da = &ldsA[(wv*32)*64];
    u16* db = &ldsB[(wv*32)*64];
    for (int k0 = 0; k0 < Ktot; k0 += 64){
      int kk = k0;
      if constexpr (DUAL){
        if (k0 >= K1){
          if (k0 == K1){
            pA = A2 + (long)z0*Abatch2 + (long)(lo0 + wv*32 + lr)*Arow2 + lc8*8;
            pB = B2 + (long)(nblk*128 + wv*32 + lr)*K2 + lc8*8;
            strA = Arow2; strB = K2;
          }
          kk = k0 - K1;
        }
      }
      __syncthreads();
#pragma unroll
      for (int u=0; u<4; u++) gll16(pA + (long)u*8*strA + kk, da + u*8*64);
#pragma unroll
      for (int u=0; u<4; u++) gll16(pB + (long)u*8*strB + kk, db + u*8*64);
      __syncthreads();      // drains DMA -> writes visible
      if constexpr (DUAL){ if (k0 == K1) xform(); }
      mfma_step();
    }
  } else
#endif
  {
    // predicated VGPR staging (zero-fills OOB taps), swizzled layout
    const int sr  = tid >> 1;
    const int cg  = (tid & 1)*4;
    const int pmS = mblk*128 + sr;
    const int zS  = pmS >> lgLo;
    const int loS = pmS & ((1<<lgLo)-1);
    const long aoff1 = (long)zS*Abatch1 + (long)loS*Arow1;
    long aoff2 = 0;
    if constexpr (DUAL) aoff2 = (long)zS*Abatch2 + (long)loS*Arow2;
    const int coS = nblk*128 + sr;
    const long boff1 = (long)coS*K1;
    long boff2 = 0;
    if constexpr (DUAL) boff2 = (long)coS*K2;
    const int ssw = sr & 7;

    for (int k0 = 0; k0 < Ktot; k0 += 64){
      const bool ph1 = !DUAL || (k0 < K1);
      __syncthreads();
      {
        const u16* asrc = ph1 ? (A1 + aoff1 + k0) : (A2 + aoff2 + (k0 - K1));
#pragma unroll
        for (int u=0; u<4; u++){
          const int c = cg + u;
          uint4 v; v.x=0u; v.y=0u; v.z=0u; v.w=0u;
          bool ok = true;
          if (PRED1 && ph1){
            int tap = (k0 + c*8) >> lgCin1;
            int pos = loS*S1 + tap - P1;
            ok = ((u32)pos < (u32)Lin1);
          }
          if (ok) v = *(const uint4*)(asrc + c*8);
          *(uint4*)&ldsA[sr*64 + ((c ^ ssw)*8)] = v;
        }
      }
      {
        const u16* bsrc = ph1 ? (B1 + boff1 + k0) : (B2 + boff2 + (k0 - K1));
#pragma unroll
        for (int u=0; u<4; u++){
          const int c = cg + u;
          uint4 v = *(const uint4*)(bsrc + c*8);
          *(uint4*)&ldsB[sr*64 + ((c ^ ssw)*8)] = v;
        }
      }
      __syncthreads();
      if constexpr (DUAL){ if (k0 == K1) xform(); }
      mfma_step();
    }
  }

  // epilogue: DUAL acc is already final (transform applied at boundary + id)
#pragma unroll
  for (int nt=0;nt<4;nt++){
    const int colg = nblk*128 + nbase + nt*16 + lm;
    if (colg >= Ncols) continue;
    float sc = 1.0f, bi = 0.0f;
    if constexpr (!DUAL){
      if (scale) sc = scale[colg];
      if (bias)  bi = bias[colg];
    }
#pragma unroll
    for (int mt=0;mt<4;mt++){
#pragma unroll
      for (int r=0;r<4;r++){
        const long pm = (long)mblk*128 + mbase + mt*16 + lq*4 + r;
        float v = acc[mt][nt][r];
        if constexpr (!DUAL){
          v = v*sc + bi;
          if (lrelu) v = lrelu_f(v);
        }
        if constexpr (F32OUT) ((float*)Out)[pm*Cout + colg] = v;
        else                  ((u16*)Out)[pm*Cout + colg] = f2bf(v);
      }
    }
  }
}

// --------------------------- prep kernels (fp32 -> bf16) --------------------
__global__ void bnfold_kernel(
    const float* __restrict__ bn0, const float* __restrict__ rbn1, const float* __restrict__ rbn2,
    float* s0, float* b0, float* s1, float* b1, float* s2, float* b2)
{
  const int blk = blockIdx.x, t = threadIdx.x;   // t < 256
  const float* p; float *so, *bo;
  if (blk == 0){ p = bn0; so = s0; bo = b0; }
  else if (blk <= 5){ int i = blk-1; p = rbn1 + i*1024; so = s1+i*256; bo = b1+i*256; }
  else { int i = blk-6; p = rbn2 + i*1024; so = s2+i*256; bo = b2+i*256; }
  const float g = p[t], be = p[256+t], m = p[512+t], v = p[768+t];
  const float sc = g / sqrtf(v + 1e-5f);
  so[t] = sc; bo[t] = be - m*sc;
}

__global__ void w0prep_kernel(const float* __restrict__ cw, u16* __restrict__ w0p){
  const int co = blockIdx.x, k = threadIdx.x;
  const int tp = k >> 4, ci = k & 15;
  u16 v = 0;
  if (tp < 15 && ci < 12) v = f2bf(cw[(co*12 + ci)*15 + tp]);
  w0p[co*256 + k] = v;
}

__global__ void wrprep_kernel(const float* __restrict__ c1, const float* __restrict__ c2, u16* __restrict__ wr){
  const int co = blockIdx.x, slot = blockIdx.y, ci = threadIdx.x;
  const float* src = (slot < 5) ? (c1 + (size_t)slot*589824) : (c2 + (size_t)(slot-5)*589824);
  u16* dst = wr + (size_t)slot*589824 + (size_t)co*2304;
  for (int tp=0; tp<9; tp++) dst[tp*256 + ci] = f2bf(src[(co*256 + ci)*9 + tp]);
}

__global__ void widprep_kernel(const float* __restrict__ idw, u16* __restrict__ wid){
  const int co = blockIdx.x, sl = blockIdx.y, ci = threadIdx.x;
  u16 h = f2bf(0.5f * idw[((size_t)sl*256 + co)*256 + ci]);
  u16* dst = wid + (size_t)sl*131072 + co*512;
  dst[ci] = h; dst[256 + ci] = h;
}

__global__ void x16prep_kernel(const float* __restrict__ x, u16* __restrict__ x16){
  const int p = blockIdx.x*256 + threadIdx.x;
  const int b = blockIdx.y;
  u16 v[16];
#pragma unroll
  for (int ci=0; ci<16; ci++) v[ci] = (ci < 12) ? f2bf(x[((size_t)(b*12+ci))*4096 + p]) : (u16)0;
  uint4 A4, B4;
  A4.x = v[0] | ((u32)v[1]<<16); A4.y = v[2] | ((u32)v[3]<<16);
  A4.z = v[4] | ((u32)v[5]<<16); A4.w = v[6] | ((u32)v[7]<<16);
  B4.x = v[8] | ((u32)v[9]<<16); B4.y = v[10]| ((u32)v[11]<<16);
  B4.z = v[12]| ((u32)v[13]<<16); B4.w = v[14]| ((u32)v[15]<<16);
  uint4* dst = (uint4*)&x16[((size_t)b*4096 + p)*16];
  dst[0] = A4; dst[1] = B4;
}

// generic fp32 -> bf16 cast
__global__ void castb_kernel(const float* __restrict__ src, u16* __restrict__ dst, int n){
  const int i = blockIdx.x*256 + threadIdx.x;
  if (i < n) dst[i] = f2bf(src[i]);
}

__global__ void canary_kernel(float* __restrict__ outp){
  const int idx = blockIdx.x*256 + threadIdx.x;
  if (idx < 3456) outp[idx] = 131072.0f;
}

// --------------------------- fp32 kernels (verified round 4-10) -------------
__global__ __launch_bounds__(256) void dconv1(
    const float* __restrict__ in, long inSS,
    const float* __restrict__ w, const float* __restrict__ bn, int Cst,
    const float* __restrict__ cb,
    float* __restrict__ out, long outSS,
    int KT, int S, int P, int Lin, int Lo)
{
  __shared__ float ldw[64];
  const int co = blockIdx.y, z = blockIdx.z;
  if (threadIdx.x < KT) ldw[threadIdx.x] = w[(size_t)co*KT + threadIdx.x];
  __syncthreads();
  const int o = blockIdx.x*256 + threadIdx.x;
  if (o >= Lo) return;
  const float* ip = in + (long)z*inSS;
  float acc = cb[co];
  const int base = o*S - P;
  for (int t = 0; t < KT; t++){
    const int pos = base + t;
    if ((u32)pos < (u32)Lin) acc += ldw[t]*ip[pos];
  }
  const float g = bn[co], be = bn[Cst+co], m = bn[2*Cst+co], v = bn[3*Cst+co];
  const float sc = g/sqrtf(v + 1e-5f);
  out[(long)z*outSS + (size_t)co*Lo + o] = lrelu_f((acc - m)*sc + be);
}

// attention; qkv (rows,768) fp32 -> o (rows,256) bf16; rows = 64*samples
__global__ __launch_bounds__(256) void attn2b(const float* __restrict__ qkv, u16* __restrict__ o){
  const int gt = blockIdx.x*256 + threadIdx.x;
  const int q = gt & 63, h = (gt>>6) & 7, bl = gt >> 9;
  const float* qp = qkv + ((size_t)(bl*64 + q))*768 + h*32;
  float qv[32];
#pragma unroll
  for (int d = 0; d < 32; d++) qv[d] = qp[d];
  float s[64]; float mx = -1e30f;
  const float isq = 0.17677669529663687f;        // 1/sqrt(32)
  for (int kc = 0; kc < 64; kc++){
    const float* kp = qkv + ((size_t)(bl*64 + kc))*768 + 256 + h*32;
    float dot = 0.f;
#pragma unroll
    for (int d = 0; d < 32; d++) dot += qv[d]*kp[d];
    dot *= isq; s[kc] = dot; mx = fmaxf(mx, dot);
  }
  float sum = 0.f;
  for (int kc = 0; kc < 64; kc++){ float e = __expf(s[kc]-mx); s[kc] = e; sum += e; }
  const float inv = 1.0f/sum;
  float ov[32];
#pragma unroll
  for (int d = 0; d < 32; d++) ov[d] = 0.f;
  for (int kc = 0; kc < 64; kc++){
    const float* vp = qkv + ((size_t)(bl*64 + kc))*768 + 512 + h*32;
    const float wgt = s[kc];
#pragma unroll
    for (int d = 0; d < 32; d++) ov[d] += wgt*vp[d];
  }
  u16* op = o + ((size_t)(bl*64 + q))*256 + h*32;
#pragma unroll
  for (int d = 0; d < 32; d++) op[d] = f2bf(ov[d]*inv);
}

__global__ void xmain_s(const float* __restrict__ om, float* __restrict__ xm, int b0){
  const int e = threadIdx.x, bl = blockIdx.x;
  float m = -1e30f;
  for (int s = 0; s < 64; s++) m = fmaxf(m, om[((size_t)(bl*64+s))*256 + e]);
  xm[(size_t)(b0+bl)*256 + e] = m;
}

__global__ void flutpool_s(const float* __restrict__ act, float* __restrict__ fp, int b0){
  const int c = threadIdx.x, g = blockIdx.x, bl = blockIdx.y;
  const float* a = act + ((size_t)bl*64 + c)*2048;
  float m = -1e30f;
  for (int i = 0; i < 32; i++) m = fmaxf(m, a[g*32+i]);
  fp[(size_t)(b0+bl)*4096 + c*64 + g] = m;
}
__global__ void pvcpool_s(const float* __restrict__ act, float* __restrict__ pp, int b0){
  const int c = threadIdx.x, g = blockIdx.x, bl = blockIdx.y;
  const float* a = act + ((size_t)bl*64 + c)*2048;
  float m = -1e30f;
  for (int i = 0; i < 64; i++) m = fmaxf(m, a[g*64+i]);
  pp[(size_t)(b0+bl)*2048 + c*32 + g] = m;
}

// FC dot-product: one block per output scalar (b,j); float4 K-reduction.
template<int N, int K>
__global__ __launch_bounds__(256) void fcdot_kernel(const float* __restrict__ inp,
    const float* __restrict__ w, float* __restrict__ outp)
{
  const int b = blockIdx.x, j = blockIdx.y;
  const int t = threadIdx.x;
  const float4* x4 = (const float4*)(inp + (size_t)b*K);
  const float4* w4 = (const float4*)(w   + (size_t)j*K);
  float s = 0.f;
#pragma unroll
  for (int k = t; k < K/4; k += 256){
    const float4 a = x4[k], c = w4[k];
    s += a.x*c.x + a.y*c.y + a.z*c.z + a.w*c.w;
  }
  for (int o2 = 32; o2 > 0; o2 >>= 1) s += __shfl_down(s, o2, 64);
  __shared__ float red[4];
  const int wv = t >> 6, lane = t & 63;
  if (lane == 0) red[wv] = s;
  __syncthreads();
  if (t == 0) outp[(size_t)b*N + j] = lrelu_f(red[0]+red[1]+red[2]+red[3]);
}

// DFT magnitudes via twiddle recurrence (2 sincos + 15 rotations per thread)
__global__ __launch_bounds__(256) void fft_kernel(const float* __restrict__ x, float* __restrict__ mag){
  const int blk = blockIdx.x;              // 64*256
  const int b = blk >> 8, kk = blk & 255, bin = kk + 50;
  const int t = threadIdx.x;
  const float* xp = x + ((size_t)(b*12 + 1))*4096;
  const float C = 6.283185307179586f/4096.0f;
  float cr, si;  __sincosf((float)((bin*t)   & 4095)*C, &si, &cr);
  float cS, sS;  __sincosf((float)((bin*256) & 4095)*C, &sS, &cS);
  float re = 0.f, im = 0.f;
  for (int n = t; n < 4096; n += 256){
    const float xv = xp[n];
    re += xv*cr; im += xv*si;
    const float c2 = cr*cS - si*sS;
    si = cr*sS + si*cS;
    cr = c2;
  }
  __shared__ float rr[256], ri[256];
  rr[t] = re; ri[t] = im; __syncthreads();
  for (int o2 = 128; o2 > 0; o2 >>= 1){ if (t < o2){ rr[t]+=rr[t+o2]; ri[t]+=ri[t+o2]; } __syncthreads(); }
  if (t == 0) mag[b*256 + kk] = sqrtf(rr[0]*rr[0] + ri[0]*ri[0]);
}

__global__ void rowmax_kernel(const float* __restrict__ mag, float* __restrict__ rmax){
  const int b = blockIdx.x, t = threadIdx.x;
  __shared__ float r[256];
  r[t] = mag[b*256 + t]; __syncthreads();
  for (int o2 = 128; o2 > 0; o2 >>= 1){ if (t < o2) r[t] = fmaxf(r[t], r[t+o2]); __syncthreads(); }
  if (t == 0) rmax[b] = r[0];
}

__global__ void freq_kernel(const float* __restrict__ mag, const float* __restrict__ rmax,
                            const float* __restrict__ fw, const float* __restrict__ fb,
                            float* __restrict__ outp){
  const int b = blockIdx.x, j = threadIdx.x;  // 32
  const float mx = rmax[b];
  const float sc = mx > 0.f ? 1.0f/mx : 1.0f;
  float acc = fb[j];
  for (int i = 0; i < 256; i++) acc += (mag[b*256+i]*sc) * fw[(size_t)j*256 + i];
  outp[b*32 + j] = lrelu_f(acc);
}

__global__ void final_kernel(const float* __restrict__ xm, const float* __restrict__ l,
                             const float* __restrict__ fr, const float* __restrict__ fv,
                             const float* __restrict__ pv, const float* __restrict__ fcw,
                             const float* __restrict__ fcb, float* __restrict__ outp){
  const int b = blockIdx.x, j = threadIdx.x;  // 32 threads, 27 active
  if (j >= 27) return;
  float acc = fcb[j];
  const float* wr_ = fcw + (size_t)j*396;
  for (int i = 0; i < 256; i++) acc += xm[b*256+i] * wr_[i];
  for (int i = 0; i < 12;  i++) acc += l[b*12+i]   * wr_[256+i];
  for (int i = 0; i < 32;  i++) acc += fr[b*32+i]  * wr_[268+i];
  for (int i = 0; i < 64;  i++) acc += fv[b*64+i]  * wr_[300+i];
  for (int i = 0; i < 32;  i++) acc += pv[b*32+i]  * wr_[364+i];
  outp[b*27 + j] = acc;
  outp[64*27 + b*27 + j] = 1.0f/(1.0f + __expf(-acc));
}

// --------------------------- host side --------------------------------------
extern "C" void kernel_launch(void* const* d_in, const int* in_sizes, int n_in,
                              void* d_out, int out_size, void* d_ws, size_t ws_size,
                              hipStream_t stream)
{
  const float* x       = (const float*)d_in[0];
  const float* l       = (const float*)d_in[1];
  const float* conv_w  = (const float*)d_in[2];
  const float* bn0     = (const float*)d_in[3];
  const float* rb_c1   = (const float*)d_in[4];
  const float* rb_bn1  = (const float*)d_in[5];
  const float* rb_c2   = (const float*)d_in[6];
  const float* rb_bn2  = (const float*)d_in[7];
  const float* rb_id   = (const float*)d_in[8];
  const float* in_w    = (const float*)d_in[9];
  const float* in_b    = (const float*)d_in[10];
  const float* out_w   = (const float*)d_in[11];
  const float* out_b   = (const float*)d_in[12];
  const float* flut_w  = (const float*)d_in[13];
  const float* flut_b  = (const float*)d_in[14];
  const float* flut_bn = (const float*)d_in[15];
  const float* pvc_w   = (const float*)d_in[16];
  const float* pvc_b   = (const float*)d_in[17];
  const float* pvc_bn  = (const float*)d_in[18];
  const float* w_flut2 = (const float*)d_in[19];
  const float* w_pvc2  = (const float*)d_in[20];
  const float* freq_w  = (const float*)d_in[21];
  const float* freq_b  = (const float*)d_in[22];
  const float* fc_w    = (const float*)d_in[23];
  const float* fc_b    = (const float*)d_in[24];
  float* outp = (float*)d_out;

  char* ws = (char*)d_ws;
  size_t off = 0;
  auto alloc = [&](size_t bytes)->char*{ char* p = ws + off; off = (off + bytes + 255) & ~(size_t)255; return p; };

  // ---- persistent (~16.7 MiB) ----
  u16* wr    = (u16*)alloc((size_t)10*589824*2);   // 11.25 MiB res weights [slot][co][tap*256+ci]
  u16* wid   = (u16*)alloc((size_t)5*131072*2);    //  1.25 MiB identity 2-tap weights
  u16* w0p   = (u16*)alloc(131072);                //  conv0 weights, K-padded
  u16* wqkvb = (u16*)alloc(196608*2);              //  qkv proj weights bf16 (768,256)
  u16* woutb = (u16*)alloc(65536*2);               //  out proj weights bf16 (256,256)
  u16* h5b   = (u16*)alloc((size_t)64*64*256*2);   //  2 MiB (B*64,256) bf16
  float* s0 = (float*)alloc(1024);  float* b0 = (float*)alloc(1024);
  float* s1 = (float*)alloc(5120);  float* b1 = (float*)alloc(5120);
  float* s2 = (float*)alloc(5120);  float* b2 = (float*)alloc(5120);
  float* xm    = (float*)alloc(65536);
  float* fpool = (float*)alloc((size_t)64*4096*4); // 1 MiB
  float* ppool = (float*)alloc((size_t)64*2048*4); // 0.5 MiB
  float* mag   = (float*)alloc(65536);
  float* rmax  = (float*)alloc(1024);
  float* fvecv = (float*)alloc(16384);
  float* pvecv = (float*)alloc(8192);
  float* freqv = (float*)alloc(8192);

  // ---- adaptive batch slice: chain arena = 2.625*sp MiB (bf16 activations) ----
  const size_t rem = (ws_size > off) ? (ws_size - off) : 0;
  int sp = 0;
  for (int c = 64; c >= 2; c >>= 1)
    if ((size_t)c*2752512 + (1<<20) <= rem){ sp = c; break; }
  if (sp == 0){ canary_kernel<<<14,256,0,stream>>>(outp); return; }

  u16* x16q = (u16*)alloc((size_t)sp*131072);      // (sp,4096,16) bf16
  u16* h0q  = (u16*)alloc((size_t)sp*1048576);     // (sp,2048,256) bf16
  u16* hCq  = (u16*)alloc((size_t)sp*524288);      // (sp,<=1024,256) bf16
  u16* ping = (u16*)alloc((size_t)sp*524288);
  u16* pong = (u16*)alloc((size_t)sp*524288);

  // ---- param prep (once) ----
  bnfold_kernel<<<11,256,0,stream>>>(bn0, rb_bn1, rb_bn2, s0,b0,s1,b1,s2,b2);
  w0prep_kernel<<<256,256,0,stream>>>(conv_w, w0p);
  wrprep_kernel<<<dim3(256,10),256,0,stream>>>(rb_c1, rb_c2, wr);
  widprep_kernel<<<dim3(256,5),256,0,stream>>>(rb_id, wid);
  castb_kernel<<<768,256,0,stream>>>(in_w, wqkvb, 196608);
  castb_kernel<<<256,256,0,stream>>>(out_w, woutb, 65536);

  // ---- res chain: (64/sp) slices on the MFMA engine (1D grid, XCD decode) ----
  for (int s = 0; s < 64/sp; s++){
    const float* xs = x + (size_t)s*sp*49152;
    x16prep_kernel<<<dim3(16,sp),256,0,stream>>>(xs, x16q);
    // conv0: (sp,4096,16) -> (sp,2048,256), k=15 s=2 p=7, K padded to 256
    {
      const int mm = sp*16, nn = 2;
      gemm_conv<true,false,false><<<mm*nn,256,0,stream>>>(
          x16q - 112, w0p, nullptr, nullptr, h0q, s0, b0,
          256, 0, 11, 2, 4, 7, 4096, 65536, 32, 0, 0, 256, 256, 1, mm, nn);
    }
    int Lin = 2048;
    const u16* bin = h0q;
    for (int i = 0; i < 5; i++){
      const int Lo = Lin >> 1;
      const int mm = sp*Lo/128, nn = 2;
      const int lgLo = 10 - i;
      // conv1 (k=9,s=2,p=4) + bn1 + lrelu
      gemm_conv<true,false,false><<<mm*nn,256,0,stream>>>(
          bin - 1024, wr + (size_t)i*589824, nullptr, nullptr, hCq, s1+i*256, b1+i*256,
          2304, 0, lgLo, 2, 8, 4, Lin, Lin*256, 512, 0, 0, 256, 256, 1, mm, nn);
      // conv2 (k=9,s=1,p=4) + bn2 + lrelu + fused identity (avgpool2+1x1 as 2-tap)
      if (i < 4){
        u16* bout = (i&1) ? pong : ping;
        gemm_conv<true,true,false><<<mm*nn,256,0,stream>>>(
            hCq - 1024, wr + (size_t)(5+i)*589824, bin, wid + (size_t)i*131072,
            bout, s2+i*256, b2+i*256,
            2304, 512, lgLo, 1, 8, 4, Lo, Lo*256, 256, Lin*256, 512, 256, 256, 1, mm, nn);
        bin = bout;
      } else {
        gemm_conv<true,true,false><<<mm*nn,256,0,stream>>>(
            hCq - 1024, wr + (size_t)(5+i)*589824, bin, wid + (size_t)i*131072,
            h5b + (size_t)s*sp*16384, s2+i*256, b2+i*256,
            2304, 512, lgLo, 1, 8, 4, Lo, Lo*256, 256, Lin*256, 512, 256, 256, 1, mm, nn);
      }
      Lin = Lo;
    }
  }

  // ---- MHA on MFMA GEMMs; slice if arena is small ----
  {
    const int nsl = (sp >= 8) ? 1 : 4;
    const int rows = 4096/nsl;                       // 64*samples per slice
    float* qkvF = (float*)x16q;                      // arena aliases (chain is dead)
    u16*   o_b  = (u16*)(qkvF + (size_t)rows*768);
    float* omF  = (float*)(o_b + (size_t)rows*256);
    for (int s = 0; s < nsl; s++){
      const int mm = rows/128;
      gemm_conv<false,false,true><<<mm*6,256,0,stream>>>(
          h5b + (size_t)s*rows*256, wqkvb, nullptr, nullptr, qkvF, nullptr, in_b,
          256, 0, 12, 1, 8, 0, 0, 0, 256, 0, 0, 768, 768, 0, mm, 6);
      attn2b<<<rows/32,256,0,stream>>>(qkvF, o_b);
      gemm_conv<false,false,true><<<mm*2,256,0,stream>>>(
          o_b, woutb, nullptr, nullptr, omF, nullptr, out_b,
          256, 0, 12, 1, 8, 0, 0, 0, 256, 0, 0, 256, 256, 0, mm, 2);
      xmain_s<<<rows/64,256,0,stream>>>(omF, xm, s*(rows/64));
    }
  }

  // ---- lead_II branch (fp32 direct, verified) ----
  {
    float* act = (float*)x16q;                       // arena alias
    const int nz = (sp >= 16) ? 64 : 8;              // act = nz*64*2048*4 bytes
    for (int s = 0; s < 64/nz; s++){
      const float* xs = x + ((size_t)(s*nz)*12 + 1)*4096;
      dconv1<<<dim3(8,64,nz),256,0,stream>>>(xs, 49152, flut_w, flut_bn, 64, flut_b,
                                             act, 64*2048, 15, 2, 7, 4096, 2048);
      flutpool_s<<<dim3(64,nz),64,0,stream>>>(act, fpool, s*nz);
      dconv1<<<dim3(8,64,nz),256,0,stream>>>(xs, 49152, pvc_w, pvc_bn, 64, pvc_b,
                                             act, 64*2048, 9, 2, 4, 4096, 2048);
      pvcpool_s<<<dim3(32,nz),64,0,stream>>>(act, ppool, s*nz);
    }
  }
  fcdot_kernel<64,4096><<<dim3(64,64),256,0,stream>>>(fpool, w_flut2, fvecv);
  fcdot_kernel<32,2048><<<dim3(64,32),256,0,stream>>>(ppool, w_pvc2, pvecv);

  // ---- FFT branch ----
  fft_kernel<<<16384,256,0,stream>>>(x, mag);
  rowmax_kernel<<<64,256,0,stream>>>(mag, rmax);
  freq_kernel<<<64,32,0,stream>>>(mag, rmax, freq_w, freq_b, freqv);

  // ---- combine + logits + sigmoid ----
  final_kernel<<<64,32,0,stream>>>(xm, l, freqv, fvecv, pvecv, fc_w, fc_b, outp);
  (void)in_sizes; (void)n_in; (void)out_size;
}

// Round 14
// 1213.289 us; speedup vs baseline: 1.2982x; 1.0820x over previous
//
#include <hip/hip_runtime.h>

typedef unsigned short u16;
typedef unsigned int   u32;
typedef __attribute__((ext_vector_type(8))) short short8;   // 8 x bf16 (4 VGPRs)
typedef __attribute__((ext_vector_type(4))) float f32x4;    // MFMA accumulator

__device__ __forceinline__ float bf2f(u16 u){ return __uint_as_float(((u32)u)<<16); }
__device__ __forceinline__ u16 f2bf(float f){ u32 x = __float_as_uint(f); x += 0x7fffu + ((x>>16)&1u); return (u16)(x>>16); }
__device__ __forceinline__ float lrelu_f(float v){ return v >= 0.0f ? v : 0.01f*v; }

#if defined(__has_builtin)
#if __has_builtin(__builtin_amdgcn_global_load_lds)
#define HAS_GLL 1
#endif
#endif
#ifndef HAS_GLL
#define HAS_GLL 0
#endif

#if HAS_GLL
// async global->LDS DMA, 16B per lane; LDS dst = l + lane*16 (wave-uniform l)
__device__ __forceinline__ void gll16(const u16* g, u16* l){
  __builtin_amdgcn_global_load_lds(
      (__attribute__((address_space(1))) void*)(void*)g,
      (__attribute__((address_space(3))) void*)l, 16, 0, 0);
}
#endif

// ---------------------------------------------------------------------------
// Implicit-GEMM conv (PROVEN r10/r12 config — do not touch):
// Tile 128x128, BK=64, 4 waves x (4x4 of 16x16x32 bf16 MFMA), single acc,
// XOR-swizzled LDS, global_load_lds fast path, XCD-aware 1D grid decode.
// r11 note: 128x256 full-N tile regressed (occupancy); keep 128x128.
// ---------------------------------------------------------------------------
template<bool PRED1, bool DUAL, bool F32OUT>
__global__ __launch_bounds__(256, 4) void gemm_conv(
    const u16* __restrict__ A1, const u16* __restrict__ B1,
    const u16* __restrict__ A2, const u16* __restrict__ B2,
    void* __restrict__ Out, const float* __restrict__ scale,
    const float* __restrict__ bias,
    int K1, int K2, int lgLo, int S1, int lgCin1, int P1, int Lin1,
    int Abatch1, int Arow1, int Abatch2, int Arow2,
    int Ncols, int Cout, int lrelu, int Mblks, int Nblks)
{
  __shared__ u16 ldsA[128*64];
  __shared__ u16 ldsB[128*64];
  const int tid = threadIdx.x;
  int nblk, mblk;
  {
    const int bid = blockIdx.x;
    if (Mblks & 7){ nblk = bid % Nblks; mblk = bid / Nblks; }
    else { const int grp = Nblks*8; const int g = bid/grp; const int r = bid - g*grp;
           nblk = r >> 3; mblk = g*8 + (r & 7); }
  }
  const int wv = tid >> 6, lane = tid & 63;
  const int mbase = (wv & 1)*64, nbase = (wv >> 1)*64;
  const int lq = lane >> 4, lm = lane & 15;
  const int sw = lm & 7;                            // fragment-read swizzle key

  f32x4 acc[4][4];
#pragma unroll
  for (int a_=0;a_<4;a_++)
#pragma unroll
    for (int b_=0;b_<4;b_++) acc[a_][b_] = (f32x4){0.f,0.f,0.f,0.f};

  float scv[4], biv[4];
  if constexpr (DUAL){
#pragma unroll
    for (int nt=0;nt<4;nt++){
      const int colg = nblk*128 + nbase + nt*16 + lm;   // DUAL: Ncols==Cout==256, in-range
      scv[nt] = scale[colg]; biv[nt] = bias[colg];
    }
  }

  auto mfma_step = [&](){
#pragma unroll
    for (int kk=0; kk<2; kk++){
      const int s8 = (((kk*4+lq) ^ sw) << 3);
      short8 af[4], bfr[4];
#pragma unroll
      for (int mt=0;mt<4;mt++) af[mt]  = *(const short8*)&ldsA[(mbase+mt*16+lm)*64 + s8];
#pragma unroll
      for (int nt=0;nt<4;nt++) bfr[nt] = *(const short8*)&ldsB[(nbase+nt*16+lm)*64 + s8];
#pragma unroll
      for (int mt=0;mt<4;mt++)
#pragma unroll
        for (int nt=0;nt<4;nt++)
          acc[mt][nt] = __builtin_amdgcn_mfma_f32_16x16x32_bf16(af[mt], bfr[nt], acc[mt][nt], 0,0,0);
    }
  };
  auto xform = [&](){                     // in-place epilogue at phase boundary
#pragma unroll
    for (int mt=0;mt<4;mt++)
#pragma unroll
      for (int nt=0;nt<4;nt++)
#pragma unroll
        for (int r=0;r<4;r++){
          float v = acc[mt][nt][r]*scv[nt] + biv[nt];
          acc[mt][nt][r] = lrelu ? lrelu_f(v) : v;
        }
  };

  const int Ktot = DUAL ? (K1 + K2) : K1;

  // wave-uniform interior test: unpredicated A reads for the whole m-tile?
  bool fast = (HAS_GLL != 0);
  if (PRED1 && fast){
    const int Lo = 1 << lgLo;
    if (Lo < 128) fast = false;
    else {
      const int lo0 = (mblk*128) & (Lo-1);
      const int taps = K1 >> lgCin1;
      fast = (lo0*S1 - P1 >= 0) && ((lo0+127)*S1 + taps - 1 - P1 < Lin1);
    }
  }

#if HAS_GLL
  if (fast){
    // Fast path: Lo>=128, tiles 128-aligned -> z constant per tile.
    const int pm0 = mblk*128;
    const int z0  = pm0 >> lgLo;
    const int lo0 = pm0 & ((1<<lgLo)-1);
    const int lr  = lane >> 3;
    const int lc8 = (lane & 7) ^ lr;              // swizzled chunk for this lane
    const u16* pA = A1 + (long)z0*Abatch1 + (long)(lo0 + wv*32 + lr)*Arow1 + lc8*8;
    const u16* pB = B1 + (long)(nblk*128 + wv*32 + lr)*K1 + lc8*8;
    long strA = Arow1, strB = K1;
    u16* da = &ldsA[(wv*32)*64];
    u16* db = &ldsB[(wv*32)*64];
    for (int k0 = 0; k0 < Ktot; k0 += 64){
      int kk = k0;
      if constexpr (DUAL){
        if (k0 >= K1){
          if (k0 == K1){
            pA = A2 + (long)z0*Abatch2 + (long)(lo0 + wv*32 + lr)*Arow2 + lc8*8;
            pB = B2 + (long)(nblk*128 + wv*32 + lr)*K2 + lc8*8;
            strA = Arow2; strB = K2;
          }
          kk = k0 - K1;
        }
      }
      __syncthreads();
#pragma unroll
      for (int u=0; u<4; u++) gll16(pA + (long)u*8*strA + kk, da + u*8*64);
#pragma unroll
      for (int u=0; u<4; u++) gll16(pB + (long)u*8*strB + kk, db + u*8*64);
      __syncthreads();      // drains DMA -> writes visible
      if constexpr (DUAL){ if (k0 == K1) xform(); }
      mfma_step();
    }
  } else
#endif
  {
    // predicated VGPR staging (zero-fills OOB taps), swizzled layout
    const int sr  = tid >> 1;
    const int cg  = (tid & 1)*4;
    const int pmS = mblk*128 + sr;
    const int zS  = pmS >> lgLo;
    const int loS = pmS & ((1<<lgLo)-1);
    const long aoff1 = (long)zS*Abatch1 + (long)loS*Arow1;
    long aoff2 = 0;
    if constexpr (DUAL) aoff2 = (long)zS*Abatch2 + (long)loS*Arow2;
    const int coS = nblk*128 + sr;
    const long boff1 = (long)coS*K1;
    long boff2 = 0;
    if constexpr (DUAL) boff2 = (long)coS*K2;
    const int ssw = sr & 7;

    for (int k0 = 0; k0 < Ktot; k0 += 64){
      const bool ph1 = !DUAL || (k0 < K1);
      __syncthreads();
      {
        const u16* asrc = ph1 ? (A1 + aoff1 + k0) : (A2 + aoff2 + (k0 - K1));
#pragma unroll
        for (int u=0; u<4; u++){
          const int c = cg + u;
          uint4 v; v.x=0u; v.y=0u; v.z=0u; v.w=0u;
          bool ok = true;
          if (PRED1 && ph1){
            int tap = (k0 + c*8) >> lgCin1;
            int pos = loS*S1 + tap - P1;
            ok = ((u32)pos < (u32)Lin1);
          }
          if (ok) v = *(const uint4*)(asrc + c*8);
          *(uint4*)&ldsA[sr*64 + ((c ^ ssw)*8)] = v;
        }
      }
      {
        const u16* bsrc = ph1 ? (B1 + boff1 + k0) : (B2 + boff2 + (k0 - K1));
#pragma unroll
        for (int u=0; u<4; u++){
          const int c = cg + u;
          uint4 v = *(const uint4*)(bsrc + c*8);
          *(uint4*)&ldsB[sr*64 + ((c ^ ssw)*8)] = v;
        }
      }
      __syncthreads();
      if constexpr (DUAL){ if (k0 == K1) xform(); }
      mfma_step();
    }
  }

  // epilogue: DUAL acc is already final (transform applied at boundary + id)
#pragma unroll
  for (int nt=0;nt<4;nt++){
    const int colg = nblk*128 + nbase + nt*16 + lm;
    if (colg >= Ncols) continue;
    float sc = 1.0f, bi = 0.0f;
    if constexpr (!DUAL){
      if (scale) sc = scale[colg];
      if (bias)  bi = bias[colg];
    }
#pragma unroll
    for (int mt=0;mt<4;mt++){
#pragma unroll
      for (int r=0;r<4;r++){
        const long pm = (long)mblk*128 + mbase + mt*16 + lq*4 + r;
        float v = acc[mt][nt][r];
        if constexpr (!DUAL){
          v = v*sc + bi;
          if (lrelu) v = lrelu_f(v);
        }
        if constexpr (F32OUT) ((float*)Out)[pm*Cout + colg] = v;
        else                  ((u16*)Out)[pm*Cout + colg] = f2bf(v);
      }
    }
  }
}

// --------------------------- prep kernels (fp32 -> bf16) --------------------
__global__ void bnfold_kernel(
    const float* __restrict__ bn0, const float* __restrict__ rbn1, const float* __restrict__ rbn2,
    float* s0, float* b0, float* s1, float* b1, float* s2, float* b2)
{
  const int blk = blockIdx.x, t = threadIdx.x;   // t < 256
  const float* p; float *so, *bo;
  if (blk == 0){ p = bn0; so = s0; bo = b0; }
  else if (blk <= 5){ int i = blk-1; p = rbn1 + i*1024; so = s1+i*256; bo = b1+i*256; }
  else { int i = blk-6; p = rbn2 + i*1024; so = s2+i*256; bo = b2+i*256; }
  const float g = p[t], be = p[256+t], m = p[512+t], v = p[768+t];
  const float sc = g / sqrtf(v + 1e-5f);
  so[t] = sc; bo[t] = be - m*sc;
}

__global__ void w0prep_kernel(const float* __restrict__ cw, u16* __restrict__ w0p){
  const int co = blockIdx.x, k = threadIdx.x;
  const int tp = k >> 4, ci = k & 15;
  u16 v = 0;
  if (tp < 15 && ci < 12) v = f2bf(cw[(co*12 + ci)*15 + tp]);
  w0p[co*256 + k] = v;
}

// coalesced: threads walk the 2304-elem source row contiguously
__global__ void wrprep_kernel(const float* __restrict__ c1, const float* __restrict__ c2, u16* __restrict__ wr){
  const int co = blockIdx.x, slot = blockIdx.y;
  const float* src = (slot < 5) ? (c1 + (size_t)slot*589824 + (size_t)co*2304)
                                : (c2 + (size_t)(slot-5)*589824 + (size_t)co*2304);
  u16* dst = wr + (size_t)slot*589824 + (size_t)co*2304;
  for (int k = threadIdx.x; k < 2304; k += 256){
    const int ci = k/9, tp = k - ci*9;
    dst[tp*256 + ci] = f2bf(src[k]);
  }
}

__global__ void widprep_kernel(const float* __restrict__ idw, u16* __restrict__ wid){
  const int co = blockIdx.x, sl = blockIdx.y, ci = threadIdx.x;
  u16 h = f2bf(0.5f * idw[((size_t)sl*256 + co)*256 + ci]);
  u16* dst = wid + (size_t)sl*131072 + co*512;
  dst[ci] = h; dst[256 + ci] = h;
}

__global__ void x16prep_kernel(const float* __restrict__ x, u16* __restrict__ x16){
  const int p = blockIdx.x*256 + threadIdx.x;
  const int b = blockIdx.y;
  u16 v[16];
#pragma unroll
  for (int ci=0; ci<16; ci++) v[ci] = (ci < 12) ? f2bf(x[((size_t)(b*12+ci))*4096 + p]) : (u16)0;
  uint4 A4, B4;
  A4.x = v[0] | ((u32)v[1]<<16); A4.y = v[2] | ((u32)v[3]<<16);
  A4.z = v[4] | ((u32)v[5]<<16); A4.w = v[6] | ((u32)v[7]<<16);
  B4.x = v[8] | ((u32)v[9]<<16); B4.y = v[10]| ((u32)v[11]<<16);
  B4.z = v[12]| ((u32)v[13]<<16); B4.w = v[14]| ((u32)v[15]<<16);
  uint4* dst = (uint4*)&x16[((size_t)b*4096 + p)*16];
  dst[0] = A4; dst[1] = B4;
}

// generic fp32 -> bf16 cast
__global__ void castb_kernel(const float* __restrict__ src, u16* __restrict__ dst, int n){
  const int i = blockIdx.x*256 + threadIdx.x;
  if (i < n) dst[i] = f2bf(src[i]);
}

__global__ void canary_kernel(float* __restrict__ outp){
  const int idx = blockIdx.x*256 + threadIdx.x;
  if (idx < 3456) outp[idx] = 131072.0f;
}

// --------------------------- fp32 kernels -----------------------------------
__global__ __launch_bounds__(256) void dconv1(
    const float* __restrict__ in, long inSS,
    const float* __restrict__ w, const float* __restrict__ bn, int Cst,
    const float* __restrict__ cb,
    float* __restrict__ out, long outSS,
    int KT, int S, int P, int Lin, int Lo)
{
  __shared__ float ldw[64];
  const int co = blockIdx.y, z = blockIdx.z;
  if (threadIdx.x < KT) ldw[threadIdx.x] = w[(size_t)co*KT + threadIdx.x];
  __syncthreads();
  const int o = blockIdx.x*256 + threadIdx.x;
  if (o >= Lo) return;
  const float* ip = in + (long)z*inSS;
  float acc = cb[co];
  const int base = o*S - P;
  for (int t = 0; t < KT; t++){
    const int pos = base + t;
    if ((u32)pos < (u32)Lin) acc += ldw[t]*ip[pos];
  }
  const float g = bn[co], be = bn[Cst+co], m = bn[2*Cst+co], v = bn[3*Cst+co];
  const float sc = g/sqrtf(v + 1e-5f);
  out[(long)z*outSS + (size_t)co*Lo + o] = lrelu_f((acc - m)*sc + be);
}

// attention v3: one wave per (sample, head); K,V staged in LDS.
// qkv rows (64*nb, 768) fp32 -> o (64*nb, 256) bf16
__global__ __launch_bounds__(64) void attn3(const float* __restrict__ qkv, u16* __restrict__ o){
  const int bh = blockIdx.x;
  const int b = bh >> 3, h = bh & 7;
  __shared__ float Ks[2048], Vs[2048];
  const int t = threadIdx.x;
  for (int e = t; e < 2048; e += 64){
    const int r = e >> 5, c = e & 31;
    const size_t base = ((size_t)(b*64 + r))*768 + h*32 + c;
    Ks[e] = qkv[base + 256];
    Vs[e] = qkv[base + 512];
  }
  __syncthreads();
  float qv[32];
  const float* qp = qkv + ((size_t)(b*64 + t))*768 + h*32;
#pragma unroll
  for (int d = 0; d < 32; d++) qv[d] = qp[d];
  float s[64]; float mx = -1e30f;
  const float isq = 0.17677669529663687f;        // 1/sqrt(32)
  for (int kc = 0; kc < 64; kc++){
    const float* kr = &Ks[kc*32];
    float dot = 0.f;
#pragma unroll
    for (int d = 0; d < 32; d++) dot += qv[d]*kr[d];
    dot *= isq; s[kc] = dot; mx = fmaxf(mx, dot);
  }
  float sum = 0.f;
  for (int kc = 0; kc < 64; kc++){ float e = __expf(s[kc]-mx); s[kc] = e; sum += e; }
  const float inv = 1.0f/sum;
  float ov[32];
#pragma unroll
  for (int d = 0; d < 32; d++) ov[d] = 0.f;
  for (int kc = 0; kc < 64; kc++){
    const float* vr = &Vs[kc*32];
    const float wgt = s[kc];
#pragma unroll
    for (int d = 0; d < 32; d++) ov[d] += wgt*vr[d];
  }
  u16* op = o + ((size_t)(b*64 + t))*256 + h*32;
#pragma unroll
  for (int d = 0; d < 32; d++) op[d] = f2bf(ov[d]*inv);
}

__global__ void xmain_s(const float* __restrict__ om, float* __restrict__ xm, int b0){
  const int e = threadIdx.x, bl = blockIdx.x;
  float m = -1e30f;
  for (int s = 0; s < 64; s++) m = fmaxf(m, om[((size_t)(bl*64+s))*256 + e]);
  xm[(size_t)(b0+bl)*256 + e] = m;
}

// pools v3: coalesced — block (c, bl), 256 threads x 8 consecutive floats
__global__ __launch_bounds__(256) void flutpool_s(const float* __restrict__ act, float* __restrict__ fp, int b0){
  const int c = blockIdx.x, bl = blockIdx.y, t = threadIdx.x;
  const float4* a4 = (const float4*)(act + ((size_t)bl*64 + c)*2048);
  float4 v0 = a4[t*2], v1 = a4[t*2+1];
  float m = fmaxf(fmaxf(fmaxf(v0.x,v0.y),fmaxf(v0.z,v0.w)),
                  fmaxf(fmaxf(v1.x,v1.y),fmaxf(v1.z,v1.w)));
  m = fmaxf(m, __shfl_down(m, 1, 64));
  m = fmaxf(m, __shfl_down(m, 2, 64));
  if ((t & 3) == 0) fp[(size_t)(b0+bl)*4096 + c*64 + (t>>2)] = m;   // group g = t/4 (32 elems)
}
__global__ __launch_bounds__(256) void pvcpool_s(const float* __restrict__ act, float* __restrict__ pp, int b0){
  const int c = blockIdx.x, bl = blockIdx.y, t = threadIdx.x;
  const float4* a4 = (const float4*)(act + ((size_t)bl*64 + c)*2048);
  float4 v0 = a4[t*2], v1 = a4[t*2+1];
  float m = fmaxf(fmaxf(fmaxf(v0.x,v0.y),fmaxf(v0.z,v0.w)),
                  fmaxf(fmaxf(v1.x,v1.y),fmaxf(v1.z,v1.w)));
  m = fmaxf(m, __shfl_down(m, 1, 64));
  m = fmaxf(m, __shfl_down(m, 2, 64));
  m = fmaxf(m, __shfl_down(m, 4, 64));
  if ((t & 7) == 0) pp[(size_t)(b0+bl)*2048 + c*32 + (t>>3)] = m;   // group g = t/8 (64 elems)
}

// FC dot-product: one block per output scalar (b,j); float4 K-reduction.
template<int N, int K>
__global__ __launch_bounds__(256) void fcdot_kernel(const float* __restrict__ inp,
    const float* __restrict__ w, float* __restrict__ outp)
{
  const int b = blockIdx.x, j = blockIdx.y;
  const int t = threadIdx.x;
  const float4* x4 = (const float4*)(inp + (size_t)b*K);
  const float4* w4 = (const float4*)(w   + (size_t)j*K);
  float s = 0.f;
#pragma unroll
  for (int k = t; k < K/4; k += 256){
    const float4 a = x4[k], c = w4[k];
    s += a.x*c.x + a.y*c.y + a.z*c.z + a.w*c.w;
  }
  for (int o2 = 32; o2 > 0; o2 >>= 1) s += __shfl_down(s, o2, 64);
  __shared__ float red[4];
  const int wv = t >> 6, lane = t & 63;
  if (lane == 0) red[wv] = s;
  __syncthreads();
  if (t == 0) outp[(size_t)b*N + j] = lrelu_f(red[0]+red[1]+red[2]+red[3]);
}

// DFT magnitudes via twiddle recurrence (2 sincos + 15 rotations per thread)
__global__ __launch_bounds__(256) void fft_kernel(const float* __restrict__ x, float* __restrict__ mag){
  const int blk = blockIdx.x;              // 64*256
  const int b = blk >> 8, kk = blk & 255, bin = kk + 50;
  const int t = threadIdx.x;
  const float* xp = x + ((size_t)(b*12 + 1))*4096;
  const float C = 6.283185307179586f/4096.0f;
  float cr, si;  __sincosf((float)((bin*t)   & 4095)*C, &si, &cr);
  float cS, sS;  __sincosf((float)((bin*256) & 4095)*C, &sS, &cS);
  float re = 0.f, im = 0.f;
  for (int n = t; n < 4096; n += 256){
    const float xv = xp[n];
    re += xv*cr; im += xv*si;
    const float c2 = cr*cS - si*sS;
    si = cr*sS + si*cS;
    cr = c2;
  }
  __shared__ float rr[256], ri[256];
  rr[t] = re; ri[t] = im; __syncthreads();
  for (int o2 = 128; o2 > 0; o2 >>= 1){ if (t < o2){ rr[t]+=rr[t+o2]; ri[t]+=ri[t+o2]; } __syncthreads(); }
  if (t == 0) mag[b*256 + kk] = sqrtf(rr[0]*rr[0] + ri[0]*ri[0]);
}

__global__ void rowmax_kernel(const float* __restrict__ mag, float* __restrict__ rmax){
  const int b = blockIdx.x, t = threadIdx.x;
  __shared__ float r[256];
  r[t] = mag[b*256 + t]; __syncthreads();
  for (int o2 = 128; o2 > 0; o2 >>= 1){ if (t < o2) r[t] = fmaxf(r[t], r[t+o2]); __syncthreads(); }
  if (t == 0) rmax[b] = r[0];
}

__global__ void freq_kernel(const float* __restrict__ mag, const float* __restrict__ rmax,
                            const float* __restrict__ fw, const float* __restrict__ fb,
                            float* __restrict__ outp){
  const int b = blockIdx.x, j = threadIdx.x;  // 32
  const float mx = rmax[b];
  const float sc = mx > 0.f ? 1.0f/mx : 1.0f;
  float acc = fb[j];
  for (int i = 0; i < 256; i++) acc += (mag[b*256+i]*sc) * fw[(size_t)j*256 + i];
  outp[b*32 + j] = lrelu_f(acc);
}

__global__ void final_kernel(const float* __restrict__ xm, const float* __restrict__ l,
                             const float* __restrict__ fr, const float* __restrict__ fv,
                             const float* __restrict__ pv, const float* __restrict__ fcw,
                             const float* __restrict__ fcb, float* __restrict__ outp){
  const int b = blockIdx.x, j = threadIdx.x;  // 32 threads, 27 active
  if (j >= 27) return;
  float acc = fcb[j];
  const float* wr_ = fcw + (size_t)j*396;
  for (int i = 0; i < 256; i++) acc += xm[b*256+i] * wr_[i];
  for (int i = 0; i < 12;  i++) acc += l[b*12+i]   * wr_[256+i];
  for (int i = 0; i < 32;  i++) acc += fr[b*32+i]  * wr_[268+i];
  for (int i = 0; i < 64;  i++) acc += fv[b*64+i]  * wr_[300+i];
  for (int i = 0; i < 32;  i++) acc += pv[b*32+i]  * wr_[364+i];
  outp[b*27 + j] = acc;
  outp[64*27 + b*27 + j] = 1.0f/(1.0f + __expf(-acc));
}

// --------------------------- host side --------------------------------------
extern "C" void kernel_launch(void* const* d_in, const int* in_sizes, int n_in,
                              void* d_out, int out_size, void* d_ws, size_t ws_size,
                              hipStream_t stream)
{
  const float* x       = (const float*)d_in[0];
  const float* l       = (const float*)d_in[1];
  const float* conv_w  = (const float*)d_in[2];
  const float* bn0     = (const float*)d_in[3];
  const float* rb_c1   = (const float*)d_in[4];
  const float* rb_bn1  = (const float*)d_in[5];
  const float* rb_c2   = (const float*)d_in[6];
  const float* rb_bn2  = (const float*)d_in[7];
  const float* rb_id   = (const float*)d_in[8];
  const float* in_w    = (const float*)d_in[9];
  const float* in_b    = (const float*)d_in[10];
  const float* out_w   = (const float*)d_in[11];
  const float* out_b   = (const float*)d_in[12];
  const float* flut_w  = (const float*)d_in[13];
  const float* flut_b  = (const float*)d_in[14];
  const float* flut_bn = (const float*)d_in[15];
  const float* pvc_w   = (const float*)d_in[16];
  const float* pvc_b   = (const float*)d_in[17];
  const float* pvc_bn  = (const float*)d_in[18];
  const float* w_flut2 = (const float*)d_in[19];
  const float* w_pvc2  = (const float*)d_in[20];
  const float* freq_w  = (const float*)d_in[21];
  const float* freq_b  = (const float*)d_in[22];
  const float* fc_w    = (const float*)d_in[23];
  const float* fc_b    = (const float*)d_in[24];
  float* outp = (float*)d_out;

  char* ws = (char*)d_ws;
  size_t off = 0;
  auto alloc = [&](size_t bytes)->char*{ char* p = ws + off; off = (off + bytes + 255) & ~(size_t)255; return p; };

  // ---- persistent (~16.7 MiB) ----
  u16* wr    = (u16*)alloc((size_t)10*589824*2);   // 11.25 MiB res weights [slot][co][tap*256+ci]
  u16* wid   = (u16*)alloc((size_t)5*131072*2);    //  1.25 MiB identity 2-tap weights
  u16* w0p   = (u16*)alloc(131072);                //  conv0 weights, K-padded
  u16* wqkvb = (u16*)alloc(196608*2);              //  qkv proj weights bf16 (768,256)
  u16* woutb = (u16*)alloc(65536*2);               //  out proj weights bf16 (256,256)
  u16* h5b   = (u16*)alloc((size_t)64*64*256*2);   //  2 MiB (B*64,256) bf16
  float* s0 = (float*)alloc(1024);  float* b0 = (float*)alloc(1024);
  float* s1 = (float*)alloc(5120);  float* b1 = (float*)alloc(5120);
  float* s2 = (float*)alloc(5120);  float* b2 = (float*)alloc(5120);
  float* xm    = (float*)alloc(65536);
  float* fpool = (float*)alloc((size_t)64*4096*4); // 1 MiB
  float* ppool = (float*)alloc((size_t)64*2048*4); // 0.5 MiB
  float* mag   = (float*)alloc(65536);
  float* rmax  = (float*)alloc(1024);
  float* fvecv = (float*)alloc(16384);
  float* pvecv = (float*)alloc(8192);
  float* freqv = (float*)alloc(8192);

  // ---- adaptive batch slice: chain arena = 2.625*sp MiB (bf16 activations) ----
  const size_t rem = (ws_size > off) ? (ws_size - off) : 0;
  int sp = 0;
  for (int c = 64; c >= 2; c >>= 1)
    if ((size_t)c*2752512 + (1<<20) <= rem){ sp = c; break; }
  if (sp == 0){ canary_kernel<<<14,256,0,stream>>>(outp); return; }

  u16* x16q = (u16*)alloc((size_t)sp*131072);      // (sp,4096,16) bf16
  u16* h0q  = (u16*)alloc((size_t)sp*1048576);     // (sp,2048,256) bf16
  u16* hCq  = (u16*)alloc((size_t)sp*524288);      // (sp,<=1024,256) bf16
  u16* ping = (u16*)alloc((size_t)sp*524288);
  u16* pong = (u16*)alloc((size_t)sp*524288);

  // ---- param prep (once) ----
  bnfold_kernel<<<11,256,0,stream>>>(bn0, rb_bn1, rb_bn2, s0,b0,s1,b1,s2,b2);
  w0prep_kernel<<<256,256,0,stream>>>(conv_w, w0p);
  wrprep_kernel<<<dim3(256,10),256,0,stream>>>(rb_c1, rb_c2, wr);
  widprep_kernel<<<dim3(256,5),256,0,stream>>>(rb_id, wid);
  castb_kernel<<<768,256,0,stream>>>(in_w, wqkvb, 196608);
  castb_kernel<<<256,256,0,stream>>>(out_w, woutb, 65536);

  // ---- res chain: (64/sp) slices on the MFMA engine (1D grid, XCD decode) ----
  for (int s = 0; s < 64/sp; s++){
    const float* xs = x + (size_t)s*sp*49152;
    x16prep_kernel<<<dim3(16,sp),256,0,stream>>>(xs, x16q);
    // conv0: (sp,4096,16) -> (sp,2048,256), k=15 s=2 p=7, K padded to 256
    {
      const int mm = sp*16, nn = 2;
      gemm_conv<true,false,false><<<mm*nn,256,0,stream>>>(
          x16q - 112, w0p, nullptr, nullptr, h0q, s0, b0,
          256, 0, 11, 2, 4, 7, 4096, 65536, 32, 0, 0, 256, 256, 1, mm, nn);
    }
    int Lin = 2048;
    const u16* bin = h0q;
    for (int i = 0; i < 5; i++){
      const int Lo = Lin >> 1;
      const int mm = sp*Lo/128, nn = 2;
      const int lgLo = 10 - i;
      // conv1 (k=9,s=2,p=4) + bn1 + lrelu
      gemm_conv<true,false,false><<<mm*nn,256,0,stream>>>(
          bin - 1024, wr + (size_t)i*589824, nullptr, nullptr, hCq, s1+i*256, b1+i*256,
          2304, 0, lgLo, 2, 8, 4, Lin, Lin*256, 512, 0, 0, 256, 256, 1, mm, nn);
      // conv2 (k=9,s=1,p=4) + bn2 + lrelu + fused identity (avgpool2+1x1 as 2-tap)
      if (i < 4){
        u16* bout = (i&1) ? pong : ping;
        gemm_conv<true,true,false><<<mm*nn,256,0,stream>>>(
            hCq - 1024, wr + (size_t)(5+i)*589824, bin, wid + (size_t)i*131072,
            bout, s2+i*256, b2+i*256,
            2304, 512, lgLo, 1, 8, 4, Lo, Lo*256, 256, Lin*256, 512, 256, 256, 1, mm, nn);
        bin = bout;
      } else {
        gemm_conv<true,true,false><<<mm*nn,256,0,stream>>>(
            hCq - 1024, wr + (size_t)(5+i)*589824, bin, wid + (size_t)i*131072,
            h5b + (size_t)s*sp*16384, s2+i*256, b2+i*256,
            2304, 512, lgLo, 1, 8, 4, Lo, Lo*256, 256, Lin*256, 512, 256, 256, 1, mm, nn);
      }
      Lin = Lo;
    }
  }

  // ---- MHA on MFMA GEMMs; slice if arena is small ----
  {
    const int nsl = (sp >= 8) ? 1 : 4;
    const int rows = 4096/nsl;                       // 64*samples per slice
    float* qkvF = (float*)x16q;                      // arena aliases (chain is dead)
    u16*   o_b  = (u16*)(qkvF + (size_t)rows*768);
    float* omF  = (float*)(o_b + (size_t)rows*256);
    for (int s = 0; s < nsl; s++){
      const int mm = rows/128;
      gemm_conv<false,false,true><<<mm*6,256,0,stream>>>(
          h5b + (size_t)s*rows*256, wqkvb, nullptr, nullptr, qkvF, nullptr, in_b,
          256, 0, 12, 1, 8, 0, 0, 0, 256, 0, 0, 768, 768, 0, mm, 6);
      attn3<<<(rows/64)*8,64,0,stream>>>(qkvF, o_b);
      gemm_conv<false,false,true><<<mm*2,256,0,stream>>>(
          o_b, woutb, nullptr, nullptr, omF, nullptr, out_b,
          256, 0, 12, 1, 8, 0, 0, 0, 256, 0, 0, 256, 256, 0, mm, 2);
      xmain_s<<<rows/64,256,0,stream>>>(omF, xm, s*(rows/64));
    }
  }

  // ---- lead_II branch (fp32 direct) ----
  {
    float* act = (float*)x16q;                       // arena alias
    const int nz = (sp >= 16) ? 64 : 8;              // act = nz*64*2048*4 bytes
    for (int s = 0; s < 64/nz; s++){
      const float* xs = x + ((size_t)(s*nz)*12 + 1)*4096;
      dconv1<<<dim3(8,64,nz),256,0,stream>>>(xs, 49152, flut_w, flut_bn, 64, flut_b,
                                             act, 64*2048, 15, 2, 7, 4096, 2048);
      flutpool_s<<<dim3(64,nz),256,0,stream>>>(act, fpool, s*nz);
      dconv1<<<dim3(8,64,nz),256,0,stream>>>(xs, 49152, pvc_w, pvc_bn, 64, pvc_b,
                                             act, 64*2048, 9, 2, 4, 4096, 2048);
      pvcpool_s<<<dim3(64,nz),256,0,stream>>>(act, ppool, s*nz);   // r13 fix: 64 channels (was 32)
    }
  }
  fcdot_kernel<64,4096><<<dim3(64,64),256,0,stream>>>(fpool, w_flut2, fvecv);
  fcdot_kernel<32,2048><<<dim3(64,32),256,0,stream>>>(ppool, w_pvc2, pvecv);

  // ---- FFT branch ----
  fft_kernel<<<16384,256,0,stream>>>(x, mag);
  rowmax_kernel<<<64,256,0,stream>>>(mag, rmax);
  freq_kernel<<<64,32,0,stream>>>(mag, rmax, freq_w, freq_b, freqv);

  // ---- combine + logits + sigmoid ----
  final_kernel<<<64,32,0,stream>>>(xm, l, freqv, fvecv, pvecv, fc_w, fc_b, outp);
  (void)in_sizes; (void)n_in; (void)out_size;
}